// Round 1
// baseline (1170.928 us; speedup 1.0000x reference)
//
#include <hip/hip_runtime.h>
#include <math.h>

// ---- problem constants ----
#define DMODEL 2048
#define DINNER 2457
#define NI     2464      // padded row stride for [*, DINNER] buffers
#define GROUPS 7
#define GCH    351       // channels per group
#define DTRANK 32

// time slices (global t): xi for t=110..127 (18), z/dt/ys for t=120..127 (8),
// xc (post-conv) for chunk-local 17..31 -> 15 steps.
#define NROW_XI 1152     // 18*64
#define NROW_XC 960      // 15*64
#define NROW_Z  512      // 8*64

// ---------------- generic f32 NT GEMM: C[m,n] = sum_k A[m,k]*B[n,k] + bias[n]
// M must be a multiple of 64. N, K arbitrary.
__global__ __launch_bounds__(256)
void gemm_nt_f32(const float* __restrict__ A, int lda,
                 const float* __restrict__ B, int ldb,
                 const float* __restrict__ bias,
                 float* __restrict__ C, int ldc,
                 int M, int N, int K)
{
    __shared__ float As[16][68];
    __shared__ float Bs[16][68];
    const int tid = threadIdx.x;
    const int tx = tid & 15, ty = tid >> 4;
    const int m0 = blockIdx.y * 64, n0 = blockIdx.x * 64;
    float acc[4][4] = {};
    for (int k0 = 0; k0 < K; k0 += 16) {
#pragma unroll
        for (int u = 0; u < 4; ++u) {
            int idx = u * 256 + tid;
            int r = idx >> 4, kk = idx & 15;
            int gk = k0 + kk;
            float av = 0.f, bv = 0.f;
            if (gk < K) {
                av = A[(size_t)(m0 + r) * lda + gk];
                int nn = n0 + r;
                bv = (nn < N) ? B[(size_t)nn * ldb + gk] : 0.f;
            }
            As[kk][r] = av;
            Bs[kk][r] = bv;
        }
        __syncthreads();
#pragma unroll
        for (int kk = 0; kk < 16; ++kk) {
            float4 a4 = *(const float4*)&As[kk][ty * 4];
            float4 b4 = *(const float4*)&Bs[kk][tx * 4];
            float a[4] = {a4.x, a4.y, a4.z, a4.w};
            float b[4] = {b4.x, b4.y, b4.z, b4.w};
#pragma unroll
            for (int i = 0; i < 4; ++i)
#pragma unroll
                for (int j = 0; j < 4; ++j)
                    acc[i][j] = fmaf(a[i], b[j], acc[i][j]);
        }
        __syncthreads();
    }
#pragma unroll
    for (int i = 0; i < 4; ++i) {
        int m = m0 + ty * 4 + i;
#pragma unroll
        for (int j = 0; j < 4; ++j) {
            int n = n0 + tx * 4 + j;
            if (n < N)
                C[(size_t)m * ldc + n] = acc[i][j] + (bias ? bias[n] : 0.f);
        }
    }
}

// ---------------- grouped causal conv (taps as shifted-row GEMMs) + SiLU
// xc[r, g*351+oc] = silu( b_conv[..] + sum_{k=0..3} sum_i xi[r+64k, g*351+i]*Wc[(g*351+oc), i, k] )
__global__ __launch_bounds__(256)
void conv_silu(const float* __restrict__ xi,   // [1152, NI]
               const float* __restrict__ Wc,   // [DINNER, GCH, 4]
               const float* __restrict__ bc,   // [DINNER]
               float* __restrict__ xc)         // [960, NI]
{
    __shared__ float As[16][68];
    __shared__ float Bs[16][68];
    const int tid = threadIdx.x;
    const int tx = tid & 15, ty = tid >> 4;
    const int n0 = blockIdx.x * 64;      // out-channel tile within group
    const int m0 = blockIdx.y * 64;      // row tile of 960
    const int g  = blockIdx.z;
    float acc[4][4] = {};
    for (int k = 0; k < 4; ++k) {
        for (int i0 = 0; i0 < GCH; i0 += 16) {
#pragma unroll
            for (int u = 0; u < 4; ++u) {
                int idx = u * 256 + tid;
                int r = idx >> 4, kk = idx & 15;
                int i = i0 + kk;
                float av = 0.f, bv = 0.f;
                if (i < GCH) {
                    av = xi[(size_t)(m0 + r + 64 * k) * NI + g * GCH + i];
                    int oc = n0 + r;
                    bv = (oc < GCH) ? Wc[((size_t)(g * GCH + oc) * GCH + i) * 4 + k] : 0.f;
                }
                As[kk][r] = av;
                Bs[kk][r] = bv;
            }
            __syncthreads();
#pragma unroll
            for (int kk = 0; kk < 16; ++kk) {
                float4 a4 = *(const float4*)&As[kk][ty * 4];
                float4 b4 = *(const float4*)&Bs[kk][tx * 4];
                float a[4] = {a4.x, a4.y, a4.z, a4.w};
                float b[4] = {b4.x, b4.y, b4.z, b4.w};
#pragma unroll
                for (int i = 0; i < 4; ++i)
#pragma unroll
                    for (int j = 0; j < 4; ++j)
                        acc[i][j] = fmaf(a[i], b[j], acc[i][j]);
            }
            __syncthreads();
        }
    }
#pragma unroll
    for (int i = 0; i < 4; ++i) {
        int m = m0 + ty * 4 + i;
#pragma unroll
        for (int j = 0; j < 4; ++j) {
            int oc = n0 + tx * 4 + j;
            if (oc < GCH) {
                float v = acc[i][j] + bc[g * GCH + oc];
                float s = v / (1.f + expf(-v));      // silu
                xc[(size_t)m * NI + g * GCH + oc] = s;
            }
        }
    }
}

// ---------------- dt = softplus(xp32 @ W_dt^T) + 1e-4
__global__ __launch_bounds__(256)
void dt_kernel(const float* __restrict__ xp,   // [512, 32]
               const float* __restrict__ Wdt,  // [DINNER, 32]
               float* __restrict__ dt)         // [512, NI]
{
    __shared__ float xrow[32];
    const int row = blockIdx.y;
    const int o = blockIdx.x * 256 + threadIdx.x;
    if (threadIdx.x < 32) xrow[threadIdx.x] = xp[row * 32 + threadIdx.x];
    __syncthreads();
    if (o >= DINNER) return;
    float s = 0.f;
#pragma unroll
    for (int k = 0; k < 32; ++k) s = fmaf(xrow[k], Wdt[o * 32 + k], s);
    float sp = fmaxf(s, 0.f) + log1pf(expf(-fabsf(s)));   // stable softplus
    dt[(size_t)row * NI + o] = sp + 1e-4f;
}

// ---------------- window-softmax + gate + mean over last 8 steps
__global__ __launch_bounds__(256)
void fuse_kernel(const float* __restrict__ xc,  // [960, NI]  (chunk-local 17..31)
                 const float* __restrict__ z,   // [512, NI]  (t=120..127)
                 const float* __restrict__ dt,  // [512, NI]
                 const float* __restrict__ Dp,  // [DINNER]
                 float* __restrict__ comp)      // [64, NI]
{
    const int d = blockIdx.x * 256 + threadIdx.x;
    const int b = blockIdx.y;
    if (d >= DINNER) return;
    float xcv[15];
#pragma unroll
    for (int tt = 0; tt < 15; ++tt) xcv[tt] = xc[(size_t)(tt * 64 + b) * NI + d];
    const float Dpd = Dp[d];
    float acc = 0.f;
#pragma unroll
    for (int s = 0; s < 8; ++s) {
        float dval = dt[(size_t)(s * 64 + b) * NI + d];
        float zval = z[(size_t)(s * 64 + b) * NI + d];
        // softmax over k=0..7 of dval*k, applied to xc[s+k]; stable via e=exp(-dval)
        float e = expf(-dval);
        float w = 1.f, wsum = 0.f, lsum = 0.f;
#pragma unroll
        for (int k = 7; k >= 0; --k) {
            wsum += w;
            lsum = fmaf(w, xcv[s + k], lsum);
            w *= e;
        }
        float local = lsum / wsum;
        float ys = (local + Dpd * xcv[s + 7]) / (1.f + expf(-zval));
        acc += ys;
    }
    comp[(size_t)b * NI + d] = acc * 0.125f;
}

// ---------------- layernorm over d_model
__global__ __launch_bounds__(256)
void ln_kernel(const float* __restrict__ outp,  // [64, 2048]
               const float* __restrict__ lw, const float* __restrict__ lb,
               float* __restrict__ out)
{
    const int b = blockIdx.x;
    const int tid = threadIdx.x;
    __shared__ float red[4];
    float v[8];
    float s = 0.f;
#pragma unroll
    for (int i = 0; i < 8; ++i) { v[i] = outp[b * 2048 + i * 256 + tid]; s += v[i]; }
#pragma unroll
    for (int off = 32; off; off >>= 1) s += __shfl_down(s, off);
    if ((tid & 63) == 0) red[tid >> 6] = s;
    __syncthreads();
    float mu = (red[0] + red[1] + red[2] + red[3]) / 2048.f;
    float s2 = 0.f;
#pragma unroll
    for (int i = 0; i < 8; ++i) { float dd = v[i] - mu; s2 += dd * dd; }
#pragma unroll
    for (int off = 32; off; off >>= 1) s2 += __shfl_down(s2, off);
    __syncthreads();
    if ((tid & 63) == 0) red[tid >> 6] = s2;
    __syncthreads();
    float var = (red[0] + red[1] + red[2] + red[3]) / 2048.f;
    float inv = rsqrtf(var + 1e-5f);
#pragma unroll
    for (int i = 0; i < 8; ++i) {
        int dcol = i * 256 + tid;
        out[b * 2048 + dcol] = (v[i] - mu) * inv * lw[dcol] + lb[dcol];
    }
}

extern "C" void kernel_launch(void* const* d_in, const int* in_sizes, int n_in,
                              void* d_out, int out_size, void* d_ws, size_t ws_size,
                              hipStream_t stream)
{
    const float* x      = (const float*)d_in[0];
    const float* W_in   = (const float*)d_in[1];
    const float* b_in   = (const float*)d_in[2];
    const float* W_gate = (const float*)d_in[3];
    const float* b_gate = (const float*)d_in[4];
    const float* W_conv = (const float*)d_in[5];
    const float* b_conv = (const float*)d_in[6];
    const float* W_xp   = (const float*)d_in[7];
    const float* b_xp   = (const float*)d_in[8];
    const float* W_dt   = (const float*)d_in[9];
    const float* Dp     = (const float*)d_in[10];
    const float* W_out  = (const float*)d_in[11];
    const float* b_out  = (const float*)d_in[12];
    const float* ln_w   = (const float*)d_in[13];
    const float* ln_b   = (const float*)d_in[14];
    float* out = (float*)d_out;

    float* ws = (float*)d_ws;
    float* xi   = ws;  ws += (size_t)NROW_XI * NI;
    float* xcb  = ws;  ws += (size_t)NROW_XC * NI;
    float* zb   = ws;  ws += (size_t)NROW_Z * NI;
    float* dtb  = ws;  ws += (size_t)NROW_Z * NI;
    float* xp32 = ws;  ws += (size_t)512 * 32;
    float* comp = ws;  ws += (size_t)64 * NI;
    float* outp = ws;  ws += (size_t)64 * 2048;

    // xi = x[t=110..127] @ W_in^T + b_in   (rows 110*64 .. 128*64-1 of x)
    {
        dim3 grid((DINNER + 63) / 64, NROW_XI / 64);
        gemm_nt_f32<<<grid, 256, 0, stream>>>(x + (size_t)(110 * 64) * DMODEL, DMODEL,
                                              W_in, DMODEL, b_in, xi, NI,
                                              NROW_XI, DINNER, DMODEL);
    }
    // z = x[t=120..127] @ W_gate^T + b_gate
    {
        dim3 grid((DINNER + 63) / 64, NROW_Z / 64);
        gemm_nt_f32<<<grid, 256, 0, stream>>>(x + (size_t)(120 * 64) * DMODEL, DMODEL,
                                              W_gate, DMODEL, b_gate, zb, NI,
                                              NROW_Z, DINNER, DMODEL);
    }
    // grouped causal conv + SiLU -> xc (chunk-local 17..31)
    {
        dim3 grid((GCH + 63) / 64, NROW_XC / 64, GROUPS);
        conv_silu<<<grid, 256, 0, stream>>>(xi, W_conv, b_conv, xcb);
    }
    // xp32 = xc[chunk-local 24..31] @ W_xproj[:32]^T + b_xproj[:32]
    {
        dim3 grid(1, 512 / 64);
        gemm_nt_f32<<<grid, 256, 0, stream>>>(xcb + (size_t)448 * NI, NI,
                                              W_xp, DINNER, b_xp, xp32, 32,
                                              512, 32, DINNER);
    }
    // dt = softplus(xp32 @ W_dt^T) + 1e-4
    {
        dim3 grid((DINNER + 255) / 256, 512);
        dt_kernel<<<grid, 256, 0, stream>>>(xp32, W_dt, dtb);
    }
    // window softmax + D-skip + gate + mean -> comp [64, DINNER]
    {
        dim3 grid((DINNER + 255) / 256, 64);
        fuse_kernel<<<grid, 256, 0, stream>>>(xcb, zb, dtb, Dp, comp);
    }
    // outp = comp @ W_out^T + b_out
    {
        dim3 grid(DMODEL / 64, 64 / 64);
        gemm_nt_f32<<<grid, 256, 0, stream>>>(comp, NI, W_out, DINNER, b_out,
                                              outp, DMODEL, 64, DMODEL, DINNER);
    }
    // layernorm -> d_out
    ln_kernel<<<64, 256, 0, stream>>>(outp, ln_w, ln_b, out);
}

// Round 2
// 713.870 us; speedup vs baseline: 1.6403x; 1.6403x over previous
//
#include <hip/hip_runtime.h>
#include <math.h>

// ---- problem constants ----
#define DMODEL 2048
#define DINNER 2457
#define NI     2464      // padded row stride for [*, DINNER] buffers
#define GROUPS 7
#define GCH    351       // channels per group
#define DTRANK 32

// time slices (global t): xi for t=110..127 (18), z/dt/ys for t=120..127 (8),
// xc (post-conv) for chunk-local 17..31 -> 15 steps.
#define NROW_XI 1152     // 18*64
#define NROW_XC 960      // 15*64
#define NROW_Z  512      // 8*64

#define OUT_SPLITS 12    // split-K factor for the out-projection

// ---------------- generic f32 NT GEMM: C[m,n] = sum_k A[m,k]*B[n,k] + bias[n]
// M must be a multiple of 64. N, K arbitrary.
__global__ __launch_bounds__(256)
void gemm_nt_f32(const float* __restrict__ A, int lda,
                 const float* __restrict__ B, int ldb,
                 const float* __restrict__ bias,
                 float* __restrict__ C, int ldc,
                 int M, int N, int K)
{
    __shared__ float As[16][68];
    __shared__ float Bs[16][68];
    const int tid = threadIdx.x;
    const int tx = tid & 15, ty = tid >> 4;
    const int m0 = blockIdx.y * 64, n0 = blockIdx.x * 64;
    float acc[4][4] = {};
    for (int k0 = 0; k0 < K; k0 += 16) {
#pragma unroll
        for (int u = 0; u < 4; ++u) {
            int idx = u * 256 + tid;
            int r = idx >> 4, kk = idx & 15;
            int gk = k0 + kk;
            float av = 0.f, bv = 0.f;
            if (gk < K) {
                av = A[(size_t)(m0 + r) * lda + gk];
                int nn = n0 + r;
                bv = (nn < N) ? B[(size_t)nn * ldb + gk] : 0.f;
            }
            As[kk][r] = av;
            Bs[kk][r] = bv;
        }
        __syncthreads();
#pragma unroll
        for (int kk = 0; kk < 16; ++kk) {
            float4 a4 = *(const float4*)&As[kk][ty * 4];
            float4 b4 = *(const float4*)&Bs[kk][tx * 4];
            float a[4] = {a4.x, a4.y, a4.z, a4.w};
            float b[4] = {b4.x, b4.y, b4.z, b4.w};
#pragma unroll
            for (int i = 0; i < 4; ++i)
#pragma unroll
                for (int j = 0; j < 4; ++j)
                    acc[i][j] = fmaf(a[i], b[j], acc[i][j]);
        }
        __syncthreads();
    }
#pragma unroll
    for (int i = 0; i < 4; ++i) {
        int m = m0 + ty * 4 + i;
#pragma unroll
        for (int j = 0; j < 4; ++j) {
            int n = n0 + tx * 4 + j;
            if (n < N)
                C[(size_t)m * ldc + n] = acc[i][j] + (bias ? bias[n] : 0.f);
        }
    }
}

// ---------------- split-K f32 NT GEMM (no bias): partial C per K-slice
// Cp[z][m][n] = sum_{k in slice z} A[m,k]*B[n,k]
__global__ __launch_bounds__(256)
void gemm_nt_splitk(const float* __restrict__ A, int lda,
                    const float* __restrict__ B, int ldb,
                    float* __restrict__ Cp, int ldc,
                    int M, int N, int K, int kchunk)
{
    __shared__ float As[16][68];
    __shared__ float Bs[16][68];
    const int tid = threadIdx.x;
    const int tx = tid & 15, ty = tid >> 4;
    const int m0 = blockIdx.y * 64, n0 = blockIdx.x * 64;
    const int kbeg = blockIdx.z * kchunk;
    const int kend = min(K, kbeg + kchunk);
    float* C = Cp + (size_t)blockIdx.z * M * ldc;
    float acc[4][4] = {};
    for (int k0 = kbeg; k0 < kend; k0 += 16) {
#pragma unroll
        for (int u = 0; u < 4; ++u) {
            int idx = u * 256 + tid;
            int r = idx >> 4, kk = idx & 15;
            int gk = k0 + kk;
            float av = 0.f, bv = 0.f;
            if (gk < kend) {
                av = A[(size_t)(m0 + r) * lda + gk];
                int nn = n0 + r;
                bv = (nn < N) ? B[(size_t)nn * ldb + gk] : 0.f;
            }
            As[kk][r] = av;
            Bs[kk][r] = bv;
        }
        __syncthreads();
#pragma unroll
        for (int kk = 0; kk < 16; ++kk) {
            float4 a4 = *(const float4*)&As[kk][ty * 4];
            float4 b4 = *(const float4*)&Bs[kk][tx * 4];
            float a[4] = {a4.x, a4.y, a4.z, a4.w};
            float b[4] = {b4.x, b4.y, b4.z, b4.w};
#pragma unroll
            for (int i = 0; i < 4; ++i)
#pragma unroll
                for (int j = 0; j < 4; ++j)
                    acc[i][j] = fmaf(a[i], b[j], acc[i][j]);
        }
        __syncthreads();
    }
#pragma unroll
    for (int i = 0; i < 4; ++i) {
        int m = m0 + ty * 4 + i;
#pragma unroll
        for (int j = 0; j < 4; ++j) {
            int n = n0 + tx * 4 + j;
            if (n < N)
                C[(size_t)m * ldc + n] = acc[i][j];
        }
    }
}

__global__ __launch_bounds__(256)
void splitk_reduce(const float* __restrict__ Cp, const float* __restrict__ bias,
                   float* __restrict__ C, int MN, int N, int S)
{
    int i = blockIdx.x * 256 + threadIdx.x;
    if (i >= MN) return;
    float s = 0.f;
    for (int p = 0; p < S; ++p) s += Cp[(size_t)p * MN + i];
    C[i] = s + bias[i % N];
}

// ---------------- xp32[row, o] = xc_row . W_xp[o] + b_xp[o]   (o = 0..31)
// one block per row; thread-strided K; register accumulators; shuffle reduce.
__global__ __launch_bounds__(256)
void xproj_kernel(const float* __restrict__ xc,   // [960, NI], rows 448.. = t 24..31
                  const float* __restrict__ Wxp,  // [48, DINNER] row-major
                  const float* __restrict__ bxp,
                  float* __restrict__ xp32)       // [512, 32]
{
    const int row = blockIdx.x;                   // 0..511
    const float* a = xc + (size_t)(448 + row) * NI;
    float acc[32];
#pragma unroll
    for (int o = 0; o < 32; ++o) acc[o] = 0.f;
    for (int k = threadIdx.x; k < DINNER; k += 256) {
        float av = a[k];
#pragma unroll
        for (int o = 0; o < 32; ++o)
            acc[o] = fmaf(av, Wxp[(size_t)o * DINNER + k], acc[o]);
    }
#pragma unroll
    for (int o = 0; o < 32; ++o) {
#pragma unroll
        for (int off = 32; off; off >>= 1)
            acc[o] += __shfl_down(acc[o], off);
    }
    __shared__ float red[4][32];
    const int wid = threadIdx.x >> 6, lane = threadIdx.x & 63;
    if (lane == 0) {
#pragma unroll
        for (int o = 0; o < 32; ++o) red[wid][o] = acc[o];
    }
    __syncthreads();
    if (threadIdx.x < 32) {
        int o = threadIdx.x;
        xp32[row * 32 + o] = red[0][o] + red[1][o] + red[2][o] + red[3][o] + bxp[o];
    }
}

// ---------------- grouped causal conv (taps as shifted-row GEMMs) + SiLU
__global__ __launch_bounds__(256)
void conv_silu(const float* __restrict__ xi,   // [1152, NI]
               const float* __restrict__ Wc,   // [DINNER, GCH, 4]
               const float* __restrict__ bc,   // [DINNER]
               float* __restrict__ xc)         // [960, NI]
{
    __shared__ float As[16][68];
    __shared__ float Bs[16][68];
    const int tid = threadIdx.x;
    const int tx = tid & 15, ty = tid >> 4;
    const int n0 = blockIdx.x * 64;      // out-channel tile within group
    const int m0 = blockIdx.y * 64;      // row tile of 960
    const int g  = blockIdx.z;
    float acc[4][4] = {};
    for (int k = 0; k < 4; ++k) {
        for (int i0 = 0; i0 < GCH; i0 += 16) {
#pragma unroll
            for (int u = 0; u < 4; ++u) {
                int idx = u * 256 + tid;
                int r = idx >> 4, kk = idx & 15;
                int i = i0 + kk;
                float av = 0.f, bv = 0.f;
                if (i < GCH) {
                    av = xi[(size_t)(m0 + r + 64 * k) * NI + g * GCH + i];
                    int oc = n0 + r;
                    bv = (oc < GCH) ? Wc[((size_t)(g * GCH + oc) * GCH + i) * 4 + k] : 0.f;
                }
                As[kk][r] = av;
                Bs[kk][r] = bv;
            }
            __syncthreads();
#pragma unroll
            for (int kk = 0; kk < 16; ++kk) {
                float4 a4 = *(const float4*)&As[kk][ty * 4];
                float4 b4 = *(const float4*)&Bs[kk][tx * 4];
                float a[4] = {a4.x, a4.y, a4.z, a4.w};
                float b[4] = {b4.x, b4.y, b4.z, b4.w};
#pragma unroll
                for (int i = 0; i < 4; ++i)
#pragma unroll
                    for (int j = 0; j < 4; ++j)
                        acc[i][j] = fmaf(a[i], b[j], acc[i][j]);
            }
            __syncthreads();
        }
    }
#pragma unroll
    for (int i = 0; i < 4; ++i) {
        int m = m0 + ty * 4 + i;
#pragma unroll
        for (int j = 0; j < 4; ++j) {
            int oc = n0 + tx * 4 + j;
            if (oc < GCH) {
                float v = acc[i][j] + bc[g * GCH + oc];
                float s = v / (1.f + expf(-v));      // silu
                xc[(size_t)m * NI + g * GCH + oc] = s;
            }
        }
    }
}

// ---------------- dt = softplus(xp32 @ W_dt^T) + 1e-4
__global__ __launch_bounds__(256)
void dt_kernel(const float* __restrict__ xp,   // [512, 32]
               const float* __restrict__ Wdt,  // [DINNER, 32]
               float* __restrict__ dt)         // [512, NI]
{
    __shared__ float xrow[32];
    const int row = blockIdx.y;
    const int o = blockIdx.x * 256 + threadIdx.x;
    if (threadIdx.x < 32) xrow[threadIdx.x] = xp[row * 32 + threadIdx.x];
    __syncthreads();
    if (o >= DINNER) return;
    float s = 0.f;
#pragma unroll
    for (int k = 0; k < 32; ++k) s = fmaf(xrow[k], Wdt[o * 32 + k], s);
    float sp = fmaxf(s, 0.f) + log1pf(expf(-fabsf(s)));   // stable softplus
    dt[(size_t)row * NI + o] = sp + 1e-4f;
}

// ---------------- window-softmax + gate + mean over last 8 steps
__global__ __launch_bounds__(256)
void fuse_kernel(const float* __restrict__ xc,  // [960, NI]  (chunk-local 17..31)
                 const float* __restrict__ z,   // [512, NI]  (t=120..127)
                 const float* __restrict__ dt,  // [512, NI]
                 const float* __restrict__ Dp,  // [DINNER]
                 float* __restrict__ comp)      // [64, NI]
{
    const int d = blockIdx.x * 256 + threadIdx.x;
    const int b = blockIdx.y;
    if (d >= DINNER) return;
    float xcv[15];
#pragma unroll
    for (int tt = 0; tt < 15; ++tt) xcv[tt] = xc[(size_t)(tt * 64 + b) * NI + d];
    const float Dpd = Dp[d];
    float acc = 0.f;
#pragma unroll
    for (int s = 0; s < 8; ++s) {
        float dval = dt[(size_t)(s * 64 + b) * NI + d];
        float zval = z[(size_t)(s * 64 + b) * NI + d];
        float e = expf(-dval);
        float w = 1.f, wsum = 0.f, lsum = 0.f;
#pragma unroll
        for (int k = 7; k >= 0; --k) {
            wsum += w;
            lsum = fmaf(w, xcv[s + k], lsum);
            w *= e;
        }
        float local = lsum / wsum;
        float ys = (local + Dpd * xcv[s + 7]) / (1.f + expf(-zval));
        acc += ys;
    }
    comp[(size_t)b * NI + d] = acc * 0.125f;
}

// ---------------- layernorm over d_model
__global__ __launch_bounds__(256)
void ln_kernel(const float* __restrict__ outp,  // [64, 2048]
               const float* __restrict__ lw, const float* __restrict__ lb,
               float* __restrict__ out)
{
    const int b = blockIdx.x;
    const int tid = threadIdx.x;
    __shared__ float red[4];
    float v[8];
    float s = 0.f;
#pragma unroll
    for (int i = 0; i < 8; ++i) { v[i] = outp[b * 2048 + i * 256 + tid]; s += v[i]; }
#pragma unroll
    for (int off = 32; off; off >>= 1) s += __shfl_down(s, off);
    if ((tid & 63) == 0) red[tid >> 6] = s;
    __syncthreads();
    float mu = (red[0] + red[1] + red[2] + red[3]) / 2048.f;
    float s2 = 0.f;
#pragma unroll
    for (int i = 0; i < 8; ++i) { float dd = v[i] - mu; s2 += dd * dd; }
#pragma unroll
    for (int off = 32; off; off >>= 1) s2 += __shfl_down(s2, off);
    __syncthreads();
    if ((tid & 63) == 0) red[tid >> 6] = s2;
    __syncthreads();
    float var = (red[0] + red[1] + red[2] + red[3]) / 2048.f;
    float inv = rsqrtf(var + 1e-5f);
#pragma unroll
    for (int i = 0; i < 8; ++i) {
        int dcol = i * 256 + tid;
        out[b * 2048 + dcol] = (v[i] - mu) * inv * lw[dcol] + lb[dcol];
    }
}

extern "C" void kernel_launch(void* const* d_in, const int* in_sizes, int n_in,
                              void* d_out, int out_size, void* d_ws, size_t ws_size,
                              hipStream_t stream)
{
    const float* x      = (const float*)d_in[0];
    const float* W_in   = (const float*)d_in[1];
    const float* b_in   = (const float*)d_in[2];
    const float* W_gate = (const float*)d_in[3];
    const float* b_gate = (const float*)d_in[4];
    const float* W_conv = (const float*)d_in[5];
    const float* b_conv = (const float*)d_in[6];
    const float* W_xp   = (const float*)d_in[7];
    const float* b_xp   = (const float*)d_in[8];
    const float* W_dt   = (const float*)d_in[9];
    const float* Dp     = (const float*)d_in[10];
    const float* W_out  = (const float*)d_in[11];
    const float* b_out  = (const float*)d_in[12];
    const float* ln_w   = (const float*)d_in[13];
    const float* ln_b   = (const float*)d_in[14];
    float* out = (float*)d_out;

    float* ws = (float*)d_ws;
    float* xi   = ws;  ws += (size_t)NROW_XI * NI;
    float* xcb  = ws;  ws += (size_t)NROW_XC * NI;
    float* zb   = ws;  ws += (size_t)NROW_Z * NI;
    float* dtb  = ws;  ws += (size_t)NROW_Z * NI;
    float* xp32 = ws;  ws += (size_t)512 * 32;
    float* comp = ws;  ws += (size_t)64 * NI;
    float* outp = ws;  ws += (size_t)64 * 2048;
    // split-K partials alias the xi buffer: conv is xi's last consumer and
    // runs before the out-projection in stream order.
    float* outpart = xi;   // needs 12*64*2048 = 1.57M floats < 1152*2464

    // xi = x[t=110..127] @ W_in^T + b_in
    {
        dim3 grid((DINNER + 63) / 64, NROW_XI / 64);
        gemm_nt_f32<<<grid, 256, 0, stream>>>(x + (size_t)(110 * 64) * DMODEL, DMODEL,
                                              W_in, DMODEL, b_in, xi, NI,
                                              NROW_XI, DINNER, DMODEL);
    }
    // z = x[t=120..127] @ W_gate^T + b_gate
    {
        dim3 grid((DINNER + 63) / 64, NROW_Z / 64);
        gemm_nt_f32<<<grid, 256, 0, stream>>>(x + (size_t)(120 * 64) * DMODEL, DMODEL,
                                              W_gate, DMODEL, b_gate, zb, NI,
                                              NROW_Z, DINNER, DMODEL);
    }
    // grouped causal conv + SiLU -> xc (chunk-local 17..31)
    {
        dim3 grid((GCH + 63) / 64, NROW_XC / 64, GROUPS);
        conv_silu<<<grid, 256, 0, stream>>>(xi, W_conv, b_conv, xcb);
    }
    // xp32 = xc[chunk-local 24..31] @ W_xproj[:32]^T + b_xproj[:32]
    xproj_kernel<<<512, 256, 0, stream>>>(xcb, W_xp, b_xp, xp32);
    // dt = softplus(xp32 @ W_dt^T) + 1e-4
    {
        dim3 grid((DINNER + 255) / 256, 512);
        dt_kernel<<<grid, 256, 0, stream>>>(xp32, W_dt, dtb);
    }
    // window softmax + D-skip + gate + mean -> comp [64, DINNER]
    {
        dim3 grid((DINNER + 255) / 256, 64);
        fuse_kernel<<<grid, 256, 0, stream>>>(xcb, zb, dtb, Dp, comp);
    }
    // outp = comp @ W_out^T + b_out   (split-K over 12 slices, then reduce)
    {
        const int kchunk = (DINNER + OUT_SPLITS - 1) / OUT_SPLITS;  // 205
        dim3 grid(DMODEL / 64, 64 / 64, OUT_SPLITS);
        gemm_nt_splitk<<<grid, 256, 0, stream>>>(comp, NI, W_out, DINNER,
                                                 outpart, DMODEL,
                                                 64, DMODEL, DINNER, kchunk);
        splitk_reduce<<<(64 * DMODEL + 255) / 256, 256, 0, stream>>>(
            outpart, b_out, outp, 64 * DMODEL, DMODEL, OUT_SPLITS);
    }
    // layernorm -> d_out
    ln_kernel<<<64, 256, 0, stream>>>(outp, ln_w, ln_b, out);
}

// Round 3
// 184.362 us; speedup vs baseline: 6.3512x; 3.8721x over previous
//
#include <hip/hip_runtime.h>
#include <math.h>
#include <stdint.h>

// ---- problem constants ----
#define DMODEL 2048
#define DINNER 2457
#define NI     2464      // padded row stride for [*, DINNER] f32 buffers (=7*352)
#define GROUPS 7
#define GCH    351       // channels per group
#define GP     352       // K-padded channels per group (bf16 layouts)
#define GNP    384       // N-padded channels per group (conv B rows, 3x128 tiles)
#define NROW_XI 1152     // 18*64 rows (t=110..127)
#define NROW_Z  512      // 8*64 rows (t=120..127)
#define NCAT   5120      // fused GEMM N: W_in -> [0,2560), W_gate -> [2560,5120)
#define GATE0  2560
#define OUT_SPLITS 12
#define CONV_PLANE (GROUPS * GNP * GP)   // per-tap conv-B plane elems (2688*352)

typedef __attribute__((ext_vector_type(8))) __bf16 bf16x8;
typedef __attribute__((ext_vector_type(4))) float f32x4;
typedef __attribute__((ext_vector_type(8))) unsigned short ushort8;

__device__ inline unsigned short f2bf(float f) {
    union { float f; unsigned int u; } v; v.f = f;
    unsigned int u = v.u;
    return (unsigned short)((u + 0x7FFFu + ((u >> 16) & 1u)) >> 16);  // RNE
}

// ---------------- casts ----------------
__global__ __launch_bounds__(256)
void cast_x(const float* __restrict__ src, unsigned short* __restrict__ dst)
{
    size_t t = (size_t)blockIdx.x * 256 + threadIdx.x;   // each handles 8 elems
    const float4* s = (const float4*)src + t * 2;
    float4 a = s[0], b = s[1];
    ushort8 o;
    o[0]=f2bf(a.x); o[1]=f2bf(a.y); o[2]=f2bf(a.z); o[3]=f2bf(a.w);
    o[4]=f2bf(b.x); o[5]=f2bf(b.y); o[6]=f2bf(b.z); o[7]=f2bf(b.w);
    *(ushort8*)(dst + t * 8) = o;
}

__global__ __launch_bounds__(256)
void cast_wcat(const float* __restrict__ Win, const float* __restrict__ Wg,
               unsigned short* __restrict__ dst)
{
    size_t t = (size_t)blockIdx.x * 256 + threadIdx.x;   // elem8 index in matrix
    const float* src = blockIdx.y ? Wg : Win;
    size_t elem = t * 8;
    size_t doff = elem + (blockIdx.y ? (size_t)GATE0 * DMODEL : 0);
    const float4* s = (const float4*)(src + elem);
    float4 a = s[0], b = s[1];
    ushort8 o;
    o[0]=f2bf(a.x); o[1]=f2bf(a.y); o[2]=f2bf(a.z); o[3]=f2bf(a.w);
    o[4]=f2bf(b.x); o[5]=f2bf(b.y); o[6]=f2bf(b.z); o[7]=f2bf(b.w);
    *(ushort8*)(dst + doff) = o;
}

// W_conv [2457][351][4] f32 -> 4 planes [7*384][352] bf16 (K-contiguous per tap)
__global__ __launch_bounds__(256)
void cast_wconv(const float* __restrict__ Wc, unsigned short* __restrict__ dst)
{
    int t = blockIdx.x * 256 + threadIdx.x;
    if (t >= DINNER * GCH) return;
    int oc = t / GCH, i = t - oc * GCH;
    float4 w = *(const float4*)(Wc + (size_t)t * 4);
    int g = oc / GCH, ol = oc - g * GCH;
    size_t base = (size_t)(g * GNP + ol) * GP + i;
    dst[0 * (size_t)CONV_PLANE + base] = f2bf(w.x);
    dst[1 * (size_t)CONV_PLANE + base] = f2bf(w.y);
    dst[2 * (size_t)CONV_PLANE + base] = f2bf(w.z);
    dst[3 * (size_t)CONV_PLANE + base] = f2bf(w.w);
    if (i == GCH - 1) {   // zero the K-pad column (i=351)
        dst[0 * (size_t)CONV_PLANE + base + 1] = 0;
        dst[1 * (size_t)CONV_PLANE + base + 1] = 0;
        dst[2 * (size_t)CONV_PLANE + base + 1] = 0;
        dst[3 * (size_t)CONV_PLANE + base + 1] = 0;
    }
}

// ---------------- fused xi|z bf16 MFMA GEMM ----------------
// C[m,n] = sum_k A[m,k]*Bcat[n,k];  n<2560 -> xi (bf16, conv layout, +bias_in)
//                                   n>=2560 -> z (f32, rows t>=120 only, +bias_gate)
__global__ __launch_bounds__(256)
void gemm_mfma_fused(const unsigned short* __restrict__ A,   // [1152][2048] bf16
                     const unsigned short* __restrict__ B,   // [5120][2048] bf16
                     const float* __restrict__ b_in,
                     const float* __restrict__ b_gate,
                     unsigned short* __restrict__ xi,        // [1152][NI] bf16 group-padded
                     float* __restrict__ zb)                 // [512][NI] f32
{
    __shared__ unsigned short Asm[128 * 40];   // +16B/row pad kills bank conflicts
    __shared__ unsigned short Bsm[128 * 40];
    const int tid = threadIdx.x;
    const int w = tid >> 6, l = tid & 63;
    const int l15 = l & 15, l4 = l >> 4;
    const int wm = w >> 1, wn = w & 1;
    const int m0 = blockIdx.y * 128, n0 = blockIdx.x * 128;
    const int r0 = tid >> 2, q0 = (tid & 3) * 8;   // staging chunk: row, k-offset

    const size_t aBase = (size_t)(m0 + r0) * DMODEL + q0;
    const size_t bBase = (size_t)(n0 + r0) * DMODEL + q0;
    uint4 ra0 = *(const uint4*)(A + aBase);
    uint4 ra1 = *(const uint4*)(A + aBase + (size_t)64 * DMODEL);
    uint4 rb0 = *(const uint4*)(B + bBase);
    uint4 rb1 = *(const uint4*)(B + bBase + (size_t)64 * DMODEL);

    f32x4 acc[4][4] = {};
    const int nK = DMODEL / 32;
    for (int ks = 0; ks < nK; ++ks) {
        *(uint4*)(Asm + r0 * 40 + q0) = ra0;
        *(uint4*)(Asm + (r0 + 64) * 40 + q0) = ra1;
        *(uint4*)(Bsm + r0 * 40 + q0) = rb0;
        *(uint4*)(Bsm + (r0 + 64) * 40 + q0) = rb1;
        __syncthreads();
        if (ks + 1 < nK) {            // issue next-tile loads; overlap with MFMA below
            size_t k = (size_t)(ks + 1) * 32;
            ra0 = *(const uint4*)(A + aBase + k);
            ra1 = *(const uint4*)(A + aBase + (size_t)64 * DMODEL + k);
            rb0 = *(const uint4*)(B + bBase + k);
            rb1 = *(const uint4*)(B + bBase + (size_t)64 * DMODEL + k);
        }
        bf16x8 af[4], bfr[4];
#pragma unroll
        for (int f = 0; f < 4; ++f) {
            af[f]  = *(const bf16x8*)(Asm + (wm * 64 + f * 16 + l15) * 40 + l4 * 8);
            bfr[f] = *(const bf16x8*)(Bsm + (wn * 64 + f * 16 + l15) * 40 + l4 * 8);
        }
#pragma unroll
        for (int i = 0; i < 4; ++i)
#pragma unroll
            for (int j = 0; j < 4; ++j)
                acc[i][j] = __builtin_amdgcn_mfma_f32_16x16x32_bf16(af[i], bfr[j], acc[i][j], 0, 0, 0);
        __syncthreads();
    }

#pragma unroll
    for (int j = 0; j < 4; ++j) {
        int colg = n0 + wn * 64 + j * 16 + l15;
        if (colg < GATE0) {
            if (colg < DINNER) {
                int g = colg / GCH, ci = colg - g * GCH;
                float bias = b_in[colg];
                size_t dco = (size_t)(g * GP + ci);
#pragma unroll
                for (int i = 0; i < 4; ++i)
#pragma unroll
                    for (int r = 0; r < 4; ++r) {
                        int row = m0 + wm * 64 + i * 16 + l4 * 4 + r;
                        xi[(size_t)row * NI + dco] = f2bf(acc[i][j][r] + bias);
                        if (ci == GCH - 1) xi[(size_t)row * NI + dco + 1] = 0;  // K-pad
                    }
            }
        } else {
            int ng = colg - GATE0;
            if (ng < DINNER) {
                float bias = b_gate[ng];
#pragma unroll
                for (int i = 0; i < 4; ++i)
#pragma unroll
                    for (int r = 0; r < 4; ++r) {
                        int row = m0 + wm * 64 + i * 16 + l4 * 4 + r;
                        if (row >= 640)
                            zb[(size_t)(row - 640) * NI + ng] = acc[i][j][r] + bias;
                    }
            }
        }
    }
}

// ---------------- grouped causal conv as 4 shifted-tap MFMA GEMMs + SiLU ----
__global__ __launch_bounds__(256)
void conv_mfma(const unsigned short* __restrict__ xi,  // [1152][NI] bf16
               const unsigned short* __restrict__ Bc,  // [4][7*384][352] bf16
               const float* __restrict__ bc,
               float* __restrict__ xcb)                // [960][NI] f32 (post-SiLU)
{
    __shared__ unsigned short Asm[64 * 40];
    __shared__ unsigned short Bsm[128 * 40];
    const int tid = threadIdx.x;
    const int w = tid >> 6, l = tid & 63;
    const int l15 = l & 15, l4 = l >> 4;
    const int wm = w >> 1, wn = w & 1;
    const int g = blockIdx.z;
    const int m0 = blockIdx.y * 64;
    const int n0l = blockIdx.x * 128;
    const int rA = tid >> 2, q0 = (tid & 3) * 8;
    const int r0 = tid >> 2;

    // flat K index kk = tap*11 + kc, kc over 352/32 steps
    auto gA = [&](int kk) {
        int tap = kk / 11, kc = kk - tap * 11;
        return (size_t)(m0 + rA + 64 * tap) * NI + g * GP + kc * 32 + q0;
    };
    auto gB = [&](int kk, int half) {
        int tap = kk / 11, kc = kk - tap * 11;
        return (size_t)tap * CONV_PLANE + (size_t)(g * GNP + n0l + r0 + half * 64) * GP + kc * 32 + q0;
    };
    uint4 ra  = *(const uint4*)(xi + gA(0));
    uint4 rb0 = *(const uint4*)(Bc + gB(0, 0));
    uint4 rb1 = *(const uint4*)(Bc + gB(0, 1));

    f32x4 acc[2][4] = {};
    for (int kk = 0; kk < 44; ++kk) {
        *(uint4*)(Asm + rA * 40 + q0) = ra;
        *(uint4*)(Bsm + r0 * 40 + q0) = rb0;
        *(uint4*)(Bsm + (r0 + 64) * 40 + q0) = rb1;
        __syncthreads();
        if (kk + 1 < 44) {
            ra  = *(const uint4*)(xi + gA(kk + 1));
            rb0 = *(const uint4*)(Bc + gB(kk + 1, 0));
            rb1 = *(const uint4*)(Bc + gB(kk + 1, 1));
        }
        bf16x8 af[2], bfr[4];
#pragma unroll
        for (int f = 0; f < 2; ++f)
            af[f] = *(const bf16x8*)(Asm + (wm * 32 + f * 16 + l15) * 40 + l4 * 8);
#pragma unroll
        for (int j = 0; j < 4; ++j)
            bfr[j] = *(const bf16x8*)(Bsm + (wn * 64 + j * 16 + l15) * 40 + l4 * 8);
#pragma unroll
        for (int i = 0; i < 2; ++i)
#pragma unroll
            for (int j = 0; j < 4; ++j)
                acc[i][j] = __builtin_amdgcn_mfma_f32_16x16x32_bf16(af[i], bfr[j], acc[i][j], 0, 0, 0);
        __syncthreads();
    }

#pragma unroll
    for (int j = 0; j < 4; ++j) {
        int ocl = n0l + wn * 64 + j * 16 + l15;
        if (ocl < GCH) {
            int ch = g * GCH + ocl;
            float bias = bc[ch];
#pragma unroll
            for (int i = 0; i < 2; ++i)
#pragma unroll
                for (int r = 0; r < 4; ++r) {
                    int row = m0 + wm * 32 + i * 16 + l4 * 4 + r;
                    float v = acc[i][j][r] + bias;
                    xcb[(size_t)row * NI + ch] = v / (1.f + expf(-v));
                }
        }
    }
}

// ---------------- xp32[row, o] = xc_row . W_xp[o] + b_xp[o]
__global__ __launch_bounds__(256)
void xproj_kernel(const float* __restrict__ xc,
                  const float* __restrict__ Wxp,
                  const float* __restrict__ bxp,
                  float* __restrict__ xp32)
{
    const int row = blockIdx.x;
    const float* a = xc + (size_t)(448 + row) * NI;
    float acc[32];
#pragma unroll
    for (int o = 0; o < 32; ++o) acc[o] = 0.f;
    for (int k = threadIdx.x; k < DINNER; k += 256) {
        float av = a[k];
#pragma unroll
        for (int o = 0; o < 32; ++o)
            acc[o] = fmaf(av, Wxp[(size_t)o * DINNER + k], acc[o]);
    }
#pragma unroll
    for (int o = 0; o < 32; ++o)
#pragma unroll
        for (int off = 32; off; off >>= 1)
            acc[o] += __shfl_down(acc[o], off);
    __shared__ float red[4][32];
    const int wid = threadIdx.x >> 6, lane = threadIdx.x & 63;
    if (lane == 0)
#pragma unroll
        for (int o = 0; o < 32; ++o) red[wid][o] = acc[o];
    __syncthreads();
    if (threadIdx.x < 32) {
        int o = threadIdx.x;
        xp32[row * 32 + o] = red[0][o] + red[1][o] + red[2][o] + red[3][o] + bxp[o];
    }
}

// ---------------- dt = softplus(xp32 @ W_dt^T) + 1e-4
__global__ __launch_bounds__(256)
void dt_kernel(const float* __restrict__ xp, const float* __restrict__ Wdt,
               float* __restrict__ dt)
{
    __shared__ float xrow[32];
    const int row = blockIdx.y;
    const int o = blockIdx.x * 256 + threadIdx.x;
    if (threadIdx.x < 32) xrow[threadIdx.x] = xp[row * 32 + threadIdx.x];
    __syncthreads();
    if (o >= DINNER) return;
    float s = 0.f;
#pragma unroll
    for (int k = 0; k < 32; ++k) s = fmaf(xrow[k], Wdt[o * 32 + k], s);
    float sp = fmaxf(s, 0.f) + log1pf(expf(-fabsf(s)));
    dt[(size_t)row * NI + o] = sp + 1e-4f;
}

// ---------------- window-softmax + gate + mean over last 8 steps
__global__ __launch_bounds__(256)
void fuse_kernel(const float* __restrict__ xc, const float* __restrict__ z,
                 const float* __restrict__ dt, const float* __restrict__ Dp,
                 float* __restrict__ comp)
{
    const int d = blockIdx.x * 256 + threadIdx.x;
    const int b = blockIdx.y;
    if (d >= DINNER) return;
    float xcv[15];
#pragma unroll
    for (int tt = 0; tt < 15; ++tt) xcv[tt] = xc[(size_t)(tt * 64 + b) * NI + d];
    const float Dpd = Dp[d];
    float acc = 0.f;
#pragma unroll
    for (int s = 0; s < 8; ++s) {
        float dval = dt[(size_t)(s * 64 + b) * NI + d];
        float zval = z[(size_t)(s * 64 + b) * NI + d];
        float e = expf(-dval);
        float w = 1.f, wsum = 0.f, lsum = 0.f;
#pragma unroll
        for (int k = 7; k >= 0; --k) {
            wsum += w;
            lsum = fmaf(w, xcv[s + k], lsum);
            w *= e;
        }
        float local = lsum / wsum;
        float ys = (local + Dpd * xcv[s + 7]) / (1.f + expf(-zval));
        acc += ys;
    }
    comp[(size_t)b * NI + d] = acc * 0.125f;
}

// ---------------- split-K out-projection (f32)
__global__ __launch_bounds__(256)
void gemm_nt_splitk(const float* __restrict__ A, int lda,
                    const float* __restrict__ B, int ldb,
                    float* __restrict__ Cp, int ldc,
                    int M, int N, int K, int kchunk)
{
    __shared__ float As[16][68];
    __shared__ float Bs[16][68];
    const int tid = threadIdx.x;
    const int tx = tid & 15, ty = tid >> 4;
    const int m0 = blockIdx.y * 64, n0 = blockIdx.x * 64;
    const int kbeg = blockIdx.z * kchunk;
    const int kend = min(K, kbeg + kchunk);
    float* C = Cp + (size_t)blockIdx.z * M * ldc;
    float acc[4][4] = {};
    for (int k0 = kbeg; k0 < kend; k0 += 16) {
#pragma unroll
        for (int u = 0; u < 4; ++u) {
            int idx = u * 256 + tid;
            int r = idx >> 4, kk = idx & 15;
            int gk = k0 + kk;
            float av = 0.f, bv = 0.f;
            if (gk < kend) {
                av = A[(size_t)(m0 + r) * lda + gk];
                int nn = n0 + r;
                bv = (nn < N) ? B[(size_t)nn * ldb + gk] : 0.f;
            }
            As[kk][r] = av;
            Bs[kk][r] = bv;
        }
        __syncthreads();
#pragma unroll
        for (int kk = 0; kk < 16; ++kk) {
            float4 a4 = *(const float4*)&As[kk][ty * 4];
            float4 b4 = *(const float4*)&Bs[kk][tx * 4];
            float a[4] = {a4.x, a4.y, a4.z, a4.w};
            float b[4] = {b4.x, b4.y, b4.z, b4.w};
#pragma unroll
            for (int i = 0; i < 4; ++i)
#pragma unroll
                for (int j = 0; j < 4; ++j)
                    acc[i][j] = fmaf(a[i], b[j], acc[i][j]);
        }
        __syncthreads();
    }
#pragma unroll
    for (int i = 0; i < 4; ++i) {
        int m = m0 + ty * 4 + i;
#pragma unroll
        for (int j = 0; j < 4; ++j) {
            int n = n0 + tx * 4 + j;
            if (n < N) C[(size_t)m * ldc + n] = acc[i][j];
        }
    }
}

__global__ __launch_bounds__(256)
void splitk_reduce(const float* __restrict__ Cp, const float* __restrict__ bias,
                   float* __restrict__ C, int MN, int N, int S)
{
    int i = blockIdx.x * 256 + threadIdx.x;
    if (i >= MN) return;
    float s = 0.f;
    for (int p = 0; p < S; ++p) s += Cp[(size_t)p * MN + i];
    C[i] = s + bias[i % N];
}

// ---------------- layernorm over d_model
__global__ __launch_bounds__(256)
void ln_kernel(const float* __restrict__ outp,
               const float* __restrict__ lw, const float* __restrict__ lb,
               float* __restrict__ out)
{
    const int b = blockIdx.x;
    const int tid = threadIdx.x;
    __shared__ float red[4];
    float v[8];
    float s = 0.f;
#pragma unroll
    for (int i = 0; i < 8; ++i) { v[i] = outp[b * 2048 + i * 256 + tid]; s += v[i]; }
#pragma unroll
    for (int off = 32; off; off >>= 1) s += __shfl_down(s, off);
    if ((tid & 63) == 0) red[tid >> 6] = s;
    __syncthreads();
    float mu = (red[0] + red[1] + red[2] + red[3]) / 2048.f;
    float s2 = 0.f;
#pragma unroll
    for (int i = 0; i < 8; ++i) { float dd = v[i] - mu; s2 += dd * dd; }
#pragma unroll
    for (int off = 32; off; off >>= 1) s2 += __shfl_down(s2, off);
    __syncthreads();
    if ((tid & 63) == 0) red[tid >> 6] = s2;
    __syncthreads();
    float var = (red[0] + red[1] + red[2] + red[3]) / 2048.f;
    float inv = rsqrtf(var + 1e-5f);
#pragma unroll
    for (int i = 0; i < 8; ++i) {
        int dcol = i * 256 + tid;
        out[b * 2048 + dcol] = (v[i] - mu) * inv * lw[dcol] + lb[dcol];
    }
}

extern "C" void kernel_launch(void* const* d_in, const int* in_sizes, int n_in,
                              void* d_out, int out_size, void* d_ws, size_t ws_size,
                              hipStream_t stream)
{
    const float* x      = (const float*)d_in[0];
    const float* W_in   = (const float*)d_in[1];
    const float* b_in   = (const float*)d_in[2];
    const float* W_gate = (const float*)d_in[3];
    const float* b_gate = (const float*)d_in[4];
    const float* W_conv = (const float*)d_in[5];
    const float* b_conv = (const float*)d_in[6];
    const float* W_xp   = (const float*)d_in[7];
    const float* b_xp   = (const float*)d_in[8];
    const float* W_dt   = (const float*)d_in[9];
    const float* Dp     = (const float*)d_in[10];
    const float* W_out  = (const float*)d_in[11];
    const float* b_out  = (const float*)d_in[12];
    const float* ln_w   = (const float*)d_in[13];
    const float* ln_b   = (const float*)d_in[14];
    float* out = (float*)d_out;

    float* ws = (float*)d_ws;
    auto alloc = [&](size_t nf) { float* p = ws; ws += (nf + 255) & ~(size_t)255; return p; };
    unsigned short* A_x   = (unsigned short*)alloc((size_t)NROW_XI * DMODEL / 2);
    unsigned short* B_cat = (unsigned short*)alloc((size_t)NCAT * DMODEL / 2);
    unsigned short* B_cv  = (unsigned short*)alloc((size_t)4 * CONV_PLANE / 2);
    unsigned short* xi_bf = (unsigned short*)alloc((size_t)NROW_XI * NI / 2);
    float* zb   = alloc((size_t)NROW_Z * NI);
    float* xp32 = alloc((size_t)512 * 32);
    float* comp = alloc((size_t)64 * NI);
    float* outp = alloc((size_t)64 * 2048);
    // aliases (stream-ordered lifetime):
    float* xcb     = (float*)B_cat;                   // 960*NI f32 after fused GEMM done
    float* outpart = (float*)B_cat + (size_t)960 * NI;// 12*64*2048 f32, disjoint from xcb
    float* dtb     = (float*)B_cv;                    // 512*NI f32 after conv done

    // 1) casts
    cast_x<<<NROW_XI, 256, 0, stream>>>(x + (size_t)(110 * 64) * DMODEL, A_x);
    {
        dim3 grid(DINNER, 2);     // 2457 blocks * 256 thr * 8 elems = 2457*2048 exactly
        cast_wcat<<<grid, 256, 0, stream>>>(W_in, W_gate, B_cat);
    }
    cast_wconv<<<(DINNER * GCH + 255) / 256, 256, 0, stream>>>(W_conv, B_cv);

    // 2) fused xi|z MFMA GEMM
    {
        dim3 grid(NCAT / 128, NROW_XI / 128);   // 40 x 9
        gemm_mfma_fused<<<grid, 256, 0, stream>>>(A_x, B_cat, b_in, b_gate, xi_bf, zb);
    }
    // 3) conv MFMA + SiLU
    {
        dim3 grid(GNP / 128, 960 / 64, GROUPS); // 3 x 15 x 7
        conv_mfma<<<grid, 256, 0, stream>>>(xi_bf, B_cv, b_conv, xcb);
    }
    // 4) small chain
    xproj_kernel<<<512, 256, 0, stream>>>(xcb, W_xp, b_xp, xp32);
    {
        dim3 grid((DINNER + 255) / 256, 512);
        dt_kernel<<<grid, 256, 0, stream>>>(xp32, W_dt, dtb);
    }
    {
        dim3 grid((DINNER + 255) / 256, 64);
        fuse_kernel<<<grid, 256, 0, stream>>>(xcb, zb, dtb, Dp, comp);
    }
    // 5) out-projection (split-K) + LN
    {
        const int kchunk = (DINNER + OUT_SPLITS - 1) / OUT_SPLITS;
        dim3 grid(DMODEL / 64, 1, OUT_SPLITS);
        gemm_nt_splitk<<<grid, 256, 0, stream>>>(comp, NI, W_out, DINNER,
                                                 outpart, DMODEL, 64, DMODEL, DINNER, kchunk);
        splitk_reduce<<<(64 * DMODEL + 255) / 256, 256, 0, stream>>>(
            outpart, b_out, outp, 64 * DMODEL, DMODEL, OUT_SPLITS);
    }
    ln_kernel<<<64, 256, 0, stream>>>(outp, ln_w, ln_b, out);
}

// Round 4
// 162.182 us; speedup vs baseline: 7.2198x; 1.1368x over previous
//
#include <hip/hip_runtime.h>
#include <math.h>
#include <stdint.h>

// ---- problem constants ----
#define DMODEL 2048
#define DINNER 2457
#define NI     2464      // padded row stride for [*, DINNER] f32 buffers (=7*352)
#define GROUPS 7
#define GCH    351       // channels per group
#define GP     352       // K-padded channels per group (bf16 layouts)
#define GNP    384       // N-padded channels per group (conv B rows, 3x128 tiles)
#define NROW_XI 1152     // 18*64 rows (t=110..127)
#define NROW_Z  512      // 8*64 rows (t=120..127)
#define NCAT   5120      // fused GEMM N: W_in -> [0,2560), W_gate -> [2560,5120)
#define GATE0  2560
#define OUT_SPLITS 12
#define CONV_PLANE (GROUPS * GNP * GP)   // per-tap conv-B plane elems (2688*352)

typedef __attribute__((ext_vector_type(8))) __bf16 bf16x8;
typedef __attribute__((ext_vector_type(4))) float f32x4;
typedef __attribute__((ext_vector_type(8))) unsigned short ushort8;

__device__ inline unsigned short f2bf(float f) {
    union { float f; unsigned int u; } v; v.f = f;
    unsigned int u = v.u;
    return (unsigned short)((u + 0x7FFFu + ((u >> 16) & 1u)) >> 16);  // RNE
}

// LDS swizzle: rows of 32 shorts (64B = 4x16B slots); slot ^= (row>>1)&3.
// 16 fragment-rows -> 8 distinct bank groups x 2-way  (2-way is free, m136)
__device__ inline int lds_addr(int row, int slot) {
    return row * 32 + ((slot ^ ((row >> 1) & 3)) << 3);
}

// ---------------- merged casts ----------------
// blocks [0,1152): x slice;  [1152,6066): W_in|W_gate; [6066,9435): W_conv
#define CAST_B0 1152
#define CAST_B1 6066
#define CAST_B2 9435
__global__ __launch_bounds__(256)
void cast_all(const float* __restrict__ x110,
              const float* __restrict__ Win, const float* __restrict__ Wg,
              const float* __restrict__ Wc,
              unsigned short* __restrict__ A_x,
              unsigned short* __restrict__ B_cat,
              unsigned short* __restrict__ B_cv)
{
    int bx = blockIdx.x;
    if (bx < CAST_B0) {
        size_t t = (size_t)bx * 256 + threadIdx.x;
        const float4* s = (const float4*)x110 + t * 2;
        float4 a = s[0], b = s[1];
        ushort8 o;
        o[0]=f2bf(a.x); o[1]=f2bf(a.y); o[2]=f2bf(a.z); o[3]=f2bf(a.w);
        o[4]=f2bf(b.x); o[5]=f2bf(b.y); o[6]=f2bf(b.z); o[7]=f2bf(b.w);
        *(ushort8*)(A_x + t * 8) = o;
    } else if (bx < CAST_B1) {
        int idx = bx - CAST_B0;                 // 0..4913
        int half = idx >= DINNER;
        int cb = half ? idx - DINNER : idx;     // 0..2456
        const float* src = half ? Wg : Win;
        size_t t = (size_t)cb * 256 + threadIdx.x;
        size_t elem = t * 8;
        size_t doff = elem + (half ? (size_t)GATE0 * DMODEL : 0);
        const float4* s = (const float4*)(src + elem);
        float4 a = s[0], b = s[1];
        ushort8 o;
        o[0]=f2bf(a.x); o[1]=f2bf(a.y); o[2]=f2bf(a.z); o[3]=f2bf(a.w);
        o[4]=f2bf(b.x); o[5]=f2bf(b.y); o[6]=f2bf(b.z); o[7]=f2bf(b.w);
        *(ushort8*)(B_cat + doff) = o;
    } else {
        int t = (bx - CAST_B1) * 256 + threadIdx.x;
        if (t >= DINNER * GCH) return;
        int oc = t / GCH, i = t - oc * GCH;
        float4 w = *(const float4*)(Wc + (size_t)t * 4);
        int g = oc / GCH, ol = oc - g * GCH;
        size_t base = (size_t)(g * GNP + ol) * GP + i;
        B_cv[0 * (size_t)CONV_PLANE + base] = f2bf(w.x);
        B_cv[1 * (size_t)CONV_PLANE + base] = f2bf(w.y);
        B_cv[2 * (size_t)CONV_PLANE + base] = f2bf(w.z);
        B_cv[3 * (size_t)CONV_PLANE + base] = f2bf(w.w);
        if (i == GCH - 1) {
            B_cv[0 * (size_t)CONV_PLANE + base + 1] = 0;
            B_cv[1 * (size_t)CONV_PLANE + base + 1] = 0;
            B_cv[2 * (size_t)CONV_PLANE + base + 1] = 0;
            B_cv[3 * (size_t)CONV_PLANE + base + 1] = 0;
        }
    }
}

// ---------------- fused xi|z bf16 MFMA GEMM, 8 waves, 128x128 tile ----------
__global__ __launch_bounds__(512)
void gemm_mfma_fused(const unsigned short* __restrict__ A,   // [1152][2048] bf16
                     const unsigned short* __restrict__ B,   // [5120][2048] bf16
                     const float* __restrict__ b_in,
                     const float* __restrict__ b_gate,
                     unsigned short* __restrict__ xi,        // [1152][NI] bf16 group-padded
                     float* __restrict__ zb)                 // [512][NI] f32
{
    __shared__ unsigned short Asm[128 * 32];
    __shared__ unsigned short Bsm[128 * 32];
    const int tid = threadIdx.x;
    const int w = tid >> 6, l = tid & 63;
    const int l15 = l & 15, l4 = l >> 4;
    const int wm = w >> 2, wn = w & 3;        // wave tile: 64(M) x 32(N)
    const int m0 = blockIdx.y * 128, n0 = blockIdx.x * 128;
    const int r0 = tid >> 2, s0 = tid & 3;    // staging: 1 uint4 per thread per matrix

    const int wA = lds_addr(r0, s0);          // swizzled LDS short-offset (fixed per thread)
    const size_t aBase = (size_t)(m0 + r0) * DMODEL + s0 * 8;
    const size_t bBase = (size_t)(n0 + r0) * DMODEL + s0 * 8;
    uint4 ra = *(const uint4*)(A + aBase);
    uint4 rb = *(const uint4*)(B + bBase);

    f32x4 acc[4][2] = {};
    const int nK = DMODEL / 32;
    for (int ks = 0; ks < nK; ++ks) {
        *(uint4*)(Asm + wA) = ra;
        *(uint4*)(Bsm + wA) = rb;
        __syncthreads();
        if (ks + 1 < nK) {                    // issue next loads; overlap with MFMA
            size_t k = (size_t)(ks + 1) * 32;
            ra = *(const uint4*)(A + aBase + k);
            rb = *(const uint4*)(B + bBase + k);
        }
        bf16x8 af[4], bfr[2];
#pragma unroll
        for (int f = 0; f < 4; ++f) {
            int rowA = wm * 64 + f * 16 + l15;
            af[f] = *(const bf16x8*)(Asm + lds_addr(rowA, l4));
        }
#pragma unroll
        for (int j = 0; j < 2; ++j) {
            int rowB = wn * 32 + j * 16 + l15;
            bfr[j] = *(const bf16x8*)(Bsm + lds_addr(rowB, l4));
        }
#pragma unroll
        for (int i = 0; i < 4; ++i)
#pragma unroll
            for (int j = 0; j < 2; ++j)
                acc[i][j] = __builtin_amdgcn_mfma_f32_16x16x32_bf16(af[i], bfr[j], acc[i][j], 0, 0, 0);
        __syncthreads();
    }

#pragma unroll
    for (int j = 0; j < 2; ++j) {
        int colg = n0 + wn * 32 + j * 16 + l15;
        if (colg < GATE0) {
            if (colg < DINNER) {
                int g = colg / GCH, ci = colg - g * GCH;
                float bias = b_in[colg];
                size_t dco = (size_t)(g * GP + ci);
#pragma unroll
                for (int i = 0; i < 4; ++i)
#pragma unroll
                    for (int r = 0; r < 4; ++r) {
                        int row = m0 + wm * 64 + i * 16 + l4 * 4 + r;
                        xi[(size_t)row * NI + dco] = f2bf(acc[i][j][r] + bias);
                        if (ci == GCH - 1) xi[(size_t)row * NI + dco + 1] = 0;  // K-pad
                    }
            }
        } else {
            int ng = colg - GATE0;
            if (ng < DINNER) {
                float bias = b_gate[ng];
#pragma unroll
                for (int i = 0; i < 4; ++i)
#pragma unroll
                    for (int r = 0; r < 4; ++r) {
                        int row = m0 + wm * 64 + i * 16 + l4 * 4 + r;
                        if (row >= 640)
                            zb[(size_t)(row - 640) * NI + ng] = acc[i][j][r] + bias;
                    }
            }
        }
    }
}

// ---------------- grouped causal conv as 4 shifted-tap MFMA GEMMs + SiLU ----
__global__ __launch_bounds__(256)
void conv_mfma(const unsigned short* __restrict__ xi,  // [1152][NI] bf16
               const unsigned short* __restrict__ Bc,  // [4][7*384][352] bf16
               const float* __restrict__ bc,
               float* __restrict__ xcb)                // [960][NI] f32 (post-SiLU)
{
    __shared__ unsigned short Asm[64 * 32];
    __shared__ unsigned short Bsm[128 * 32];
    const int tid = threadIdx.x;
    const int w = tid >> 6, l = tid & 63;
    const int l15 = l & 15, l4 = l >> 4;
    const int wm = w >> 1, wn = w & 1;        // wave tile: 32(M) x 64(N)
    const int g = blockIdx.z;
    const int m0 = blockIdx.y * 64;
    const int n0l = blockIdx.x * 128;
    const int r0 = tid >> 2, s0 = tid & 3;
    const int q0 = s0 * 8;

    auto gA = [&](int kk) {
        int tap = kk / 11, kc = kk - tap * 11;
        return (size_t)(m0 + r0 + 64 * tap) * NI + g * GP + kc * 32 + q0;
    };
    auto gB = [&](int kk, int half) {
        int tap = kk / 11, kc = kk - tap * 11;
        return (size_t)tap * CONV_PLANE + (size_t)(g * GNP + n0l + r0 + half * 64) * GP + kc * 32 + q0;
    };
    uint4 ra  = *(const uint4*)(xi + gA(0));
    uint4 rb0 = *(const uint4*)(Bc + gB(0, 0));
    uint4 rb1 = *(const uint4*)(Bc + gB(0, 1));

    const int wA  = lds_addr(r0, s0);
    const int wB1 = lds_addr(r0 + 64, s0);

    f32x4 acc[2][4] = {};
    for (int kk = 0; kk < 44; ++kk) {
        *(uint4*)(Asm + wA) = ra;
        *(uint4*)(Bsm + wA) = rb0;
        *(uint4*)(Bsm + wB1) = rb1;
        __syncthreads();
        if (kk + 1 < 44) {
            ra  = *(const uint4*)(xi + gA(kk + 1));
            rb0 = *(const uint4*)(Bc + gB(kk + 1, 0));
            rb1 = *(const uint4*)(Bc + gB(kk + 1, 1));
        }
        bf16x8 af[2], bfr[4];
#pragma unroll
        for (int f = 0; f < 2; ++f) {
            int rowA = wm * 32 + f * 16 + l15;
            af[f] = *(const bf16x8*)(Asm + lds_addr(rowA, l4));
        }
#pragma unroll
        for (int j = 0; j < 4; ++j) {
            int rowB = wn * 64 + j * 16 + l15;
            bfr[j] = *(const bf16x8*)(Bsm + lds_addr(rowB, l4));
        }
#pragma unroll
        for (int i = 0; i < 2; ++i)
#pragma unroll
            for (int j = 0; j < 4; ++j)
                acc[i][j] = __builtin_amdgcn_mfma_f32_16x16x32_bf16(af[i], bfr[j], acc[i][j], 0, 0, 0);
        __syncthreads();
    }

#pragma unroll
    for (int j = 0; j < 4; ++j) {
        int ocl = n0l + wn * 64 + j * 16 + l15;
        if (ocl < GCH) {
            int ch = g * GCH + ocl;
            float bias = bc[ch];
#pragma unroll
            for (int i = 0; i < 2; ++i)
#pragma unroll
                for (int r = 0; r < 4; ++r) {
                    int row = m0 + wm * 32 + i * 16 + l4 * 4 + r;
                    float v = acc[i][j][r] + bias;
                    xcb[(size_t)row * NI + ch] = v / (1.f + expf(-v));
                }
        }
    }
}

// ---------------- fused xproj + dt: one block per row (512 rows) ----------
__global__ __launch_bounds__(256)
void xproj_dt(const float* __restrict__ xc,    // [960][NI], rows 448.. = t 24..31
              const float* __restrict__ Wxp,   // [48][DINNER]
              const float* __restrict__ bxp,
              const float* __restrict__ Wdt,   // [DINNER][32]
              float* __restrict__ dtb)         // [512][NI]
{
    const int row = blockIdx.x;
    const float* a = xc + (size_t)(448 + row) * NI;
    float acc[32];
#pragma unroll
    for (int o = 0; o < 32; ++o) acc[o] = 0.f;
    for (int k = threadIdx.x; k < DINNER; k += 256) {
        float av = a[k];
#pragma unroll
        for (int o = 0; o < 32; ++o)
            acc[o] = fmaf(av, Wxp[(size_t)o * DINNER + k], acc[o]);
    }
#pragma unroll
    for (int o = 0; o < 32; ++o)
#pragma unroll
        for (int off = 32; off; off >>= 1)
            acc[o] += __shfl_down(acc[o], off);
    __shared__ float red[4][32];
    __shared__ float xp[32];
    const int wid = threadIdx.x >> 6, lane = threadIdx.x & 63;
    if (lane == 0)
#pragma unroll
        for (int o = 0; o < 32; ++o) red[wid][o] = acc[o];
    __syncthreads();
    if (threadIdx.x < 32) {
        int o = threadIdx.x;
        xp[o] = red[0][o] + red[1][o] + red[2][o] + red[3][o] + bxp[o];
    }
    __syncthreads();
    float xr[32];
#pragma unroll
    for (int k = 0; k < 32; ++k) xr[k] = xp[k];
    for (int o = threadIdx.x; o < DINNER; o += 256) {
        const float4* wp = (const float4*)(Wdt + (size_t)o * 32);
        float s = 0.f;
#pragma unroll
        for (int q = 0; q < 8; ++q) {
            float4 wv = wp[q];
            s = fmaf(xr[q * 4 + 0], wv.x, s);
            s = fmaf(xr[q * 4 + 1], wv.y, s);
            s = fmaf(xr[q * 4 + 2], wv.z, s);
            s = fmaf(xr[q * 4 + 3], wv.w, s);
        }
        float sp = fmaxf(s, 0.f) + log1pf(expf(-fabsf(s)));
        dtb[(size_t)row * NI + o] = sp + 1e-4f;
    }
}

// ---------------- window-softmax + gate + mean over last 8 steps
__global__ __launch_bounds__(256)
void fuse_kernel(const float* __restrict__ xc, const float* __restrict__ z,
                 const float* __restrict__ dt, const float* __restrict__ Dp,
                 float* __restrict__ comp)
{
    const int d = blockIdx.x * 256 + threadIdx.x;
    const int b = blockIdx.y;
    if (d >= DINNER) return;
    float xcv[15];
#pragma unroll
    for (int tt = 0; tt < 15; ++tt) xcv[tt] = xc[(size_t)(tt * 64 + b) * NI + d];
    const float Dpd = Dp[d];
    float acc = 0.f;
#pragma unroll
    for (int s = 0; s < 8; ++s) {
        float dval = dt[(size_t)(s * 64 + b) * NI + d];
        float zval = z[(size_t)(s * 64 + b) * NI + d];
        float e = expf(-dval);
        float w = 1.f, wsum = 0.f, lsum = 0.f;
#pragma unroll
        for (int k = 7; k >= 0; --k) {
            wsum += w;
            lsum = fmaf(w, xcv[s + k], lsum);
            w *= e;
        }
        float local = lsum / wsum;
        float ys = (local + Dpd * xcv[s + 7]) / (1.f + expf(-zval));
        acc += ys;
    }
    comp[(size_t)b * NI + d] = acc * 0.125f;
}

// ---------------- split-K out-projection (f32)
__global__ __launch_bounds__(256)
void gemm_nt_splitk(const float* __restrict__ A, int lda,
                    const float* __restrict__ B, int ldb,
                    float* __restrict__ Cp, int ldc,
                    int M, int N, int K, int kchunk)
{
    __shared__ float As[16][68];
    __shared__ float Bs[16][68];
    const int tid = threadIdx.x;
    const int tx = tid & 15, ty = tid >> 4;
    const int m0 = blockIdx.y * 64, n0 = blockIdx.x * 64;
    const int kbeg = blockIdx.z * kchunk;
    const int kend = min(K, kbeg + kchunk);
    float* C = Cp + (size_t)blockIdx.z * M * ldc;
    float acc[4][4] = {};
    for (int k0 = kbeg; k0 < kend; k0 += 16) {
#pragma unroll
        for (int u = 0; u < 4; ++u) {
            int idx = u * 256 + tid;
            int r = idx >> 4, kk = idx & 15;
            int gk = k0 + kk;
            float av = 0.f, bv = 0.f;
            if (gk < kend) {
                av = A[(size_t)(m0 + r) * lda + gk];
                int nn = n0 + r;
                bv = (nn < N) ? B[(size_t)nn * ldb + gk] : 0.f;
            }
            As[kk][r] = av;
            Bs[kk][r] = bv;
        }
        __syncthreads();
#pragma unroll
        for (int kk = 0; kk < 16; ++kk) {
            float4 a4 = *(const float4*)&As[kk][ty * 4];
            float4 b4 = *(const float4*)&Bs[kk][tx * 4];
            float a[4] = {a4.x, a4.y, a4.z, a4.w};
            float b[4] = {b4.x, b4.y, b4.z, b4.w};
#pragma unroll
            for (int i = 0; i < 4; ++i)
#pragma unroll
                for (int j = 0; j < 4; ++j)
                    acc[i][j] = fmaf(a[i], b[j], acc[i][j]);
        }
        __syncthreads();
    }
#pragma unroll
    for (int i = 0; i < 4; ++i) {
        int m = m0 + ty * 4 + i;
#pragma unroll
        for (int j = 0; j < 4; ++j) {
            int n = n0 + tx * 4 + j;
            if (n < N) C[(size_t)m * ldc + n] = acc[i][j];
        }
    }
}

// ---------------- splitk-reduce + bias + layernorm fused
__global__ __launch_bounds__(256)
void ln_kernel(const float* __restrict__ Cp,    // [12][64][2048] partials
               const float* __restrict__ b_out,
               const float* __restrict__ lw, const float* __restrict__ lb,
               float* __restrict__ out)
{
    const int b = blockIdx.x;
    const int tid = threadIdx.x;
    __shared__ float red[4];
    float v[8];
    float s = 0.f;
#pragma unroll
    for (int i = 0; i < 8; ++i) {
        int col = i * 256 + tid;
        float acc = b_out[col];
#pragma unroll
        for (int p = 0; p < OUT_SPLITS; ++p)
            acc += Cp[(size_t)p * 64 * 2048 + b * 2048 + col];
        v[i] = acc; s += acc;
    }
#pragma unroll
    for (int off = 32; off; off >>= 1) s += __shfl_down(s, off);
    if ((tid & 63) == 0) red[tid >> 6] = s;
    __syncthreads();
    float mu = (red[0] + red[1] + red[2] + red[3]) / 2048.f;
    float s2 = 0.f;
#pragma unroll
    for (int i = 0; i < 8; ++i) { float dd = v[i] - mu; s2 += dd * dd; }
#pragma unroll
    for (int off = 32; off; off >>= 1) s2 += __shfl_down(s2, off);
    __syncthreads();
    if ((tid & 63) == 0) red[tid >> 6] = s2;
    __syncthreads();
    float var = (red[0] + red[1] + red[2] + red[3]) / 2048.f;
    float inv = rsqrtf(var + 1e-5f);
#pragma unroll
    for (int i = 0; i < 8; ++i) {
        int dcol = i * 256 + tid;
        out[b * 2048 + dcol] = (v[i] - mu) * inv * lw[dcol] + lb[dcol];
    }
}

extern "C" void kernel_launch(void* const* d_in, const int* in_sizes, int n_in,
                              void* d_out, int out_size, void* d_ws, size_t ws_size,
                              hipStream_t stream)
{
    const float* x      = (const float*)d_in[0];
    const float* W_in   = (const float*)d_in[1];
    const float* b_in   = (const float*)d_in[2];
    const float* W_gate = (const float*)d_in[3];
    const float* b_gate = (const float*)d_in[4];
    const float* W_conv = (const float*)d_in[5];
    const float* b_conv = (const float*)d_in[6];
    const float* W_xp   = (const float*)d_in[7];
    const float* b_xp   = (const float*)d_in[8];
    const float* W_dt   = (const float*)d_in[9];
    const float* Dp     = (const float*)d_in[10];
    const float* W_out  = (const float*)d_in[11];
    const float* b_out  = (const float*)d_in[12];
    const float* ln_w   = (const float*)d_in[13];
    const float* ln_b   = (const float*)d_in[14];
    float* out = (float*)d_out;

    float* ws = (float*)d_ws;
    auto alloc = [&](size_t nf) { float* p = ws; ws += (nf + 255) & ~(size_t)255; return p; };
    unsigned short* A_x   = (unsigned short*)alloc((size_t)NROW_XI * DMODEL / 2);
    unsigned short* B_cat = (unsigned short*)alloc((size_t)NCAT * DMODEL / 2);
    unsigned short* B_cv  = (unsigned short*)alloc((size_t)4 * CONV_PLANE / 2);
    unsigned short* xi_bf = (unsigned short*)alloc((size_t)NROW_XI * NI / 2);
    float* zb   = alloc((size_t)NROW_Z * NI);
    float* comp = alloc((size_t)64 * NI);
    // aliases (stream-ordered lifetime):
    float* xcb     = (float*)B_cat;                    // 960*NI f32, after fused GEMM done
    float* outpart = (float*)B_cat + (size_t)960 * NI; // 12*64*2048 f32, disjoint from xcb
    float* dtb     = (float*)B_cv;                     // 512*NI f32, after conv done

    // 1) merged casts
    cast_all<<<CAST_B2, 256, 0, stream>>>(x + (size_t)(110 * 64) * DMODEL,
                                          W_in, W_gate, W_conv, A_x, B_cat, B_cv);
    // 2) fused xi|z MFMA GEMM (8 waves)
    {
        dim3 grid(NCAT / 128, NROW_XI / 128);   // 40 x 9
        gemm_mfma_fused<<<grid, 512, 0, stream>>>(A_x, B_cat, b_in, b_gate, xi_bf, zb);
    }
    // 3) conv MFMA + SiLU
    {
        dim3 grid(GNP / 128, 960 / 64, GROUPS); // 3 x 15 x 7
        conv_mfma<<<grid, 256, 0, stream>>>(xi_bf, B_cv, b_conv, xcb);
    }
    // 4) fused xproj+dt, then window-softmax fuse
    xproj_dt<<<512, 256, 0, stream>>>(xcb, W_xp, b_xp, W_dt, dtb);
    {
        dim3 grid((DINNER + 255) / 256, 64);
        fuse_kernel<<<grid, 256, 0, stream>>>(xcb, zb, dtb, Dp, comp);
    }
    // 5) out-projection (split-K) + fused reduce+LN
    {
        const int kchunk = (DINNER + OUT_SPLITS - 1) / OUT_SPLITS;
        dim3 grid(DMODEL / 64, 1, OUT_SPLITS);
        gemm_nt_splitk<<<grid, 256, 0, stream>>>(comp, NI, W_out, DINNER,
                                                 outpart, DMODEL, 64, DMODEL, DINNER, kchunk);
    }
    ln_kernel<<<64, 256, 0, stream>>>(outpart, b_out, ln_w, ln_b, out);
}

// Round 5
// 157.285 us; speedup vs baseline: 7.4446x; 1.0311x over previous
//
#include <hip/hip_runtime.h>
#include <math.h>
#include <stdint.h>

// ---- problem constants ----
#define DMODEL 2048
#define DINNER 2457
#define NI     2464      // padded row stride for [*, DINNER] buffers (=7*352)
#define GROUPS 7
#define GCH    351       // channels per group
#define GP     352       // K-padded channels per group (bf16 layouts)
#define GNP    384       // N-padded channels per group (conv B rows)
#define NROW_XI 1152     // 18*64 rows (t=110..127)
#define NROW_Z  512      // 8*64 rows (t=120..127)
#define NCAT   5120      // fused GEMM N: W_in -> [0,2560), W_gate -> [2560,5120)
#define GATE0  2560
#define OUT_SPLITS 16
#define CONV_PLANE (GROUPS * GNP * GP)   // per-tap conv-B plane elems (2688*352)

typedef __attribute__((ext_vector_type(8))) __bf16 bf16x8;
typedef __attribute__((ext_vector_type(4))) float f32x4;
typedef __attribute__((ext_vector_type(8))) unsigned short ushort8;

__device__ inline unsigned short f2bf(float f) {
    union { float f; unsigned int u; } v; v.f = f;
    unsigned int u = v.u;
    return (unsigned short)((u + 0x7FFFu + ((u >> 16) & 1u)) >> 16);  // RNE
}

// LDS swizzle: rows of 32 shorts (64B = 4x16B slots); position p holds data
// slot p ^ ((row>>1)&3). Applied on the global SOURCE address at staging
// (global_load_lds writes linearly) and on the ds_read address (rule #21).
__device__ inline int lds_addr(int row, int slot) {
    return row * 32 + ((slot ^ ((row >> 1) & 3)) << 3);
}

// async global->LDS, 16B per lane; lds dest is wave-uniform base + lane*16
__device__ __forceinline__ void gload16(const unsigned short* g, unsigned short* l) {
    __builtin_amdgcn_global_load_lds(
        (const __attribute__((address_space(1))) unsigned int*)g,
        (__attribute__((address_space(3))) unsigned int*)l, 16, 0, 0);
}

// ---------------- merged casts ----------------
// blocks [0,1152): x slice;  [1152,6066): W_in|W_gate; [6066,9435): W_conv
#define CAST_B0 1152
#define CAST_B1 6066
#define CAST_B2 9435
__global__ __launch_bounds__(256)
void cast_all(const float* __restrict__ x110,
              const float* __restrict__ Win, const float* __restrict__ Wg,
              const float* __restrict__ Wc,
              unsigned short* __restrict__ A_x,
              unsigned short* __restrict__ B_cat,
              unsigned short* __restrict__ B_cv)
{
    int bx = blockIdx.x;
    if (bx < CAST_B0) {
        size_t t = (size_t)bx * 256 + threadIdx.x;
        const float4* s = (const float4*)x110 + t * 2;
        float4 a = s[0], b = s[1];
        ushort8 o;
        o[0]=f2bf(a.x); o[1]=f2bf(a.y); o[2]=f2bf(a.z); o[3]=f2bf(a.w);
        o[4]=f2bf(b.x); o[5]=f2bf(b.y); o[6]=f2bf(b.z); o[7]=f2bf(b.w);
        *(ushort8*)(A_x + t * 8) = o;
    } else if (bx < CAST_B1) {
        int idx = bx - CAST_B0;
        int half = idx >= DINNER;
        int cb = half ? idx - DINNER : idx;
        const float* src = half ? Wg : Win;
        size_t t = (size_t)cb * 256 + threadIdx.x;
        size_t elem = t * 8;
        size_t doff = elem + (half ? (size_t)GATE0 * DMODEL : 0);
        const float4* s = (const float4*)(src + elem);
        float4 a = s[0], b = s[1];
        ushort8 o;
        o[0]=f2bf(a.x); o[1]=f2bf(a.y); o[2]=f2bf(a.z); o[3]=f2bf(a.w);
        o[4]=f2bf(b.x); o[5]=f2bf(b.y); o[6]=f2bf(b.z); o[7]=f2bf(b.w);
        *(ushort8*)(B_cat + doff) = o;
    } else {
        int t = (bx - CAST_B1) * 256 + threadIdx.x;
        if (t >= DINNER * GCH) return;
        int oc = t / GCH, i = t - oc * GCH;
        float4 w = *(const float4*)(Wc + (size_t)t * 4);
        int g = oc / GCH, ol = oc - g * GCH;
        size_t base = (size_t)(g * GNP + ol) * GP + i;
        B_cv[0 * (size_t)CONV_PLANE + base] = f2bf(w.x);
        B_cv[1 * (size_t)CONV_PLANE + base] = f2bf(w.y);
        B_cv[2 * (size_t)CONV_PLANE + base] = f2bf(w.z);
        B_cv[3 * (size_t)CONV_PLANE + base] = f2bf(w.w);
        if (i == GCH - 1) {
            B_cv[0 * (size_t)CONV_PLANE + base + 1] = 0;
            B_cv[1 * (size_t)CONV_PLANE + base + 1] = 0;
            B_cv[2 * (size_t)CONV_PLANE + base + 1] = 0;
            B_cv[3 * (size_t)CONV_PLANE + base + 1] = 0;
        }
    }
}

// ---------------- fused xi|z bf16 MFMA GEMM ----------------
// tile 128(M)x64(N), 4 waves (wave-tile 64x32), global_load_lds double-buffer,
// one barrier per K-step. Grid: 360 xi-half tiles + 160 gate-half tiles
// (gate columns only needed for rows >= 640 -> m-tiles 5..8).
#define NKSTEP 64   // 2048/32
__global__ __launch_bounds__(256)
void gemm_mfma_fused(const unsigned short* __restrict__ A,   // [1152][2048] bf16
                     const unsigned short* __restrict__ B,   // [5120][2048] bf16
                     const float* __restrict__ b_in,
                     const float* __restrict__ b_gate,
                     unsigned short* __restrict__ xi,        // [1152][NI] bf16 group-padded
                     float* __restrict__ zb)                 // [512][NI] f32
{
    __shared__ unsigned short sm[2 * 192 * 32];   // 2 bufs x (A 128 + B 64 rows) x 64B
    const int tid = threadIdx.x;
    const int w = tid >> 6, l = tid & 63;
    const int l15 = l & 15, l4 = l >> 4;
    const int wm = w >> 1, wn = w & 1;
    int bid = blockIdx.x;
    int nt, mt;
    if (bid < 360) { nt = bid % 40; mt = bid / 40; }
    else { int b2 = bid - 360; nt = 40 + (b2 % 40); mt = 5 + (b2 / 40); }
    const int m0 = mt * 128, n0 = nt * 64;

    // staging lane geometry: seg = 16 rows (1KB); wave w stages A segs {w,w+4}, B seg w
    const int lr = l >> 2, slot = l & 3;
    const int rA0 = w * 16 + lr, rA1 = rA0 + 64, rB = rA0;
    const unsigned short* gA0 = A + (size_t)(m0 + rA0) * DMODEL + ((slot ^ ((rA0 >> 1) & 3)) << 3);
    const unsigned short* gA1 = A + (size_t)(m0 + rA1) * DMODEL + ((slot ^ ((rA1 >> 1) & 3)) << 3);
    const unsigned short* gB  = B + (size_t)(n0 + rB ) * DMODEL + ((slot ^ ((rB  >> 1) & 3)) << 3);
    unsigned short* dA0 = sm + w * 512;
    unsigned short* dA1 = sm + (w + 4) * 512;
    unsigned short* dB  = sm + 4096 + w * 512;

#define STAGE_G(buf, ks) do { \
    int _o = (ks) * 32, _b = (buf) * 6144; \
    gload16(gA0 + _o, dA0 + _b); \
    gload16(gA1 + _o, dA1 + _b); \
    gload16(gB  + _o, dB  + _b); } while (0)

    f32x4 acc[4][2] = {};
    STAGE_G(0, 0);
    __syncthreads();
    int cur = 0;
    for (int ks = 0; ks < NKSTEP; ++ks) {
        if (ks + 1 < NKSTEP) STAGE_G(cur ^ 1, ks + 1);   // async into other buffer
        const unsigned short* base = sm + cur * 6144;
        bf16x8 af[4], bfr[2];
#pragma unroll
        for (int f = 0; f < 4; ++f)
            af[f] = *(const bf16x8*)(base + lds_addr(wm * 64 + f * 16 + l15, l4));
#pragma unroll
        for (int j = 0; j < 2; ++j)
            bfr[j] = *(const bf16x8*)(base + 4096 + lds_addr(wn * 32 + j * 16 + l15, l4));
#pragma unroll
        for (int i = 0; i < 4; ++i)
#pragma unroll
            for (int j = 0; j < 2; ++j)
                acc[i][j] = __builtin_amdgcn_mfma_f32_16x16x32_bf16(af[i], bfr[j], acc[i][j], 0, 0, 0);
        __syncthreads();    // drains vmcnt (next buffer staged) + lgkm; all waves sync
        cur ^= 1;
    }
#undef STAGE_G

#pragma unroll
    for (int j = 0; j < 2; ++j) {
        int colg = n0 + wn * 32 + j * 16 + l15;
        if (colg < GATE0) {
            if (colg < DINNER) {
                int g = colg / GCH, ci = colg - g * GCH;
                float bias = b_in[colg];
                size_t dco = (size_t)(g * GP + ci);
#pragma unroll
                for (int i = 0; i < 4; ++i)
#pragma unroll
                    for (int r = 0; r < 4; ++r) {
                        int row = m0 + wm * 64 + i * 16 + l4 * 4 + r;
                        xi[(size_t)row * NI + dco] = f2bf(acc[i][j][r] + bias);
                        if (ci == GCH - 1) xi[(size_t)row * NI + dco + 1] = 0;  // K-pad
                    }
            }
        } else {
            int ng = colg - GATE0;
            if (ng < DINNER) {
                float bias = b_gate[ng];
#pragma unroll
                for (int i = 0; i < 4; ++i)
#pragma unroll
                    for (int r = 0; r < 4; ++r) {
                        int row = m0 + wm * 64 + i * 16 + l4 * 4 + r;
                        if (row >= 640)
                            zb[(size_t)(row - 640) * NI + ng] = acc[i][j][r] + bias;
                    }
            }
        }
    }
}

// ---------------- grouped causal conv: 4 shifted-tap MFMA GEMMs + SiLU ------
// tile 64(M)x128(N), 4 waves (wave-tile 32x64), gload_lds double-buffer.
__global__ __launch_bounds__(256)
void conv_mfma(const unsigned short* __restrict__ xi,  // [1152][NI] bf16
               const unsigned short* __restrict__ Bc,  // [4][2688][352] bf16
               const float* __restrict__ bc,
               float* __restrict__ xcb)                // [960][NI] f32 (post-SiLU)
{
    __shared__ unsigned short sm[2 * 192 * 32];   // 2 bufs x (A 64 + B 128 rows)
    const int tid = threadIdx.x;
    const int w = tid >> 6, l = tid & 63;
    const int l15 = l & 15, l4 = l >> 4;
    const int wm = w >> 1, wn = w & 1;
    const int g = blockIdx.z;
    const int m0 = blockIdx.y * 64;
    const int n0l = blockIdx.x * 128;

    const int lr = l >> 2, slot = l & 3;
    const int rA = w * 16 + lr;            // A rows 0..63 (seg w)
    const int rB0 = rA, rB1 = rA + 64;     // B rows (segs w, w+4)
    const int xoA  = (slot ^ ((rA  >> 1) & 3)) << 3;
    const int xoB0 = (slot ^ ((rB0 >> 1) & 3)) << 3;
    const int xoB1 = (slot ^ ((rB1 >> 1) & 3)) << 3;
    const unsigned short* gAb = xi + (size_t)(m0 + rA) * NI + g * GP + xoA;
    const unsigned short* gB0 = Bc + (size_t)(g * GNP + n0l + rB0) * GP + xoB0;
    const unsigned short* gB1 = Bc + (size_t)(g * GNP + n0l + rB1) * GP + xoB1;
    unsigned short* dA  = sm + w * 512;
    unsigned short* dB0 = sm + 2048 + w * 512;
    unsigned short* dB1 = sm + 2048 + (w + 4) * 512;

#define STAGE_C(buf, ks) do { \
    int _tap = (ks) / 11, _kc = (ks) - _tap * 11, _b = (buf) * 6144; \
    size_t _ao = (size_t)(64 * _tap) * NI + _kc * 32; \
    size_t _bo = (size_t)_tap * CONV_PLANE + _kc * 32; \
    gload16(gAb + _ao, dA  + _b); \
    gload16(gB0 + _bo, dB0 + _b); \
    gload16(gB1 + _bo, dB1 + _b); } while (0)

    f32x4 acc[2][4] = {};
    STAGE_C(0, 0);
    __syncthreads();
    int cur = 0;
    for (int ks = 0; ks < 44; ++ks) {
        if (ks + 1 < 44) STAGE_C(cur ^ 1, ks + 1);
        const unsigned short* base = sm + cur * 6144;
        bf16x8 af[2], bfr[4];
#pragma unroll
        for (int f = 0; f < 2; ++f)
            af[f] = *(const bf16x8*)(base + lds_addr(wm * 32 + f * 16 + l15, l4));
#pragma unroll
        for (int j = 0; j < 4; ++j)
            bfr[j] = *(const bf16x8*)(base + 2048 + lds_addr(wn * 64 + j * 16 + l15, l4));
#pragma unroll
        for (int i = 0; i < 2; ++i)
#pragma unroll
            for (int j = 0; j < 4; ++j)
                acc[i][j] = __builtin_amdgcn_mfma_f32_16x16x32_bf16(af[i], bfr[j], acc[i][j], 0, 0, 0);
        __syncthreads();
        cur ^= 1;
    }
#undef STAGE_C

#pragma unroll
    for (int j = 0; j < 4; ++j) {
        int ocl = n0l + wn * 64 + j * 16 + l15;
        if (ocl < GCH) {
            int ch = g * GCH + ocl;
            float bias = bc[ch];
#pragma unroll
            for (int i = 0; i < 2; ++i)
#pragma unroll
                for (int r = 0; r < 4; ++r) {
                    int row = m0 + wm * 32 + i * 16 + l4 * 4 + r;
                    float v = acc[i][j][r] + bias;
                    xcb[(size_t)row * NI + ch] = v / (1.f + expf(-v));
                }
        }
    }
}

// ---------------- fused xproj + dt ----------------
__global__ __launch_bounds__(256)
void xproj_dt(const float* __restrict__ xc,    // [960][NI], rows 448.. = t 24..31
              const float* __restrict__ Wxp,   // [48][DINNER]
              const float* __restrict__ bxp,
              const float* __restrict__ Wdt,   // [DINNER][32]
              float* __restrict__ dtb)         // [512][NI]
{
    const int row = blockIdx.x;
    const float* a = xc + (size_t)(448 + row) * NI;
    float acc[32];
#pragma unroll
    for (int o = 0; o < 32; ++o) acc[o] = 0.f;
    for (int k = threadIdx.x; k < DINNER; k += 256) {
        float av = a[k];
#pragma unroll
        for (int o = 0; o < 32; ++o)
            acc[o] = fmaf(av, Wxp[(size_t)o * DINNER + k], acc[o]);
    }
#pragma unroll
    for (int o = 0; o < 32; ++o)
#pragma unroll
        for (int off = 32; off; off >>= 1)
            acc[o] += __shfl_down(acc[o], off);
    __shared__ float red[4][32];
    __shared__ float xp[32];
    const int wid = threadIdx.x >> 6, lane = threadIdx.x & 63;
    if (lane == 0)
#pragma unroll
        for (int o = 0; o < 32; ++o) red[wid][o] = acc[o];
    __syncthreads();
    if (threadIdx.x < 32) {
        int o = threadIdx.x;
        xp[o] = red[0][o] + red[1][o] + red[2][o] + red[3][o] + bxp[o];
    }
    __syncthreads();
    float xr[32];
#pragma unroll
    for (int k = 0; k < 32; ++k) xr[k] = xp[k];
    for (int o = threadIdx.x; o < DINNER; o += 256) {
        const float4* wp = (const float4*)(Wdt + (size_t)o * 32);
        float s = 0.f;
#pragma unroll
        for (int q = 0; q < 8; ++q) {
            float4 wv = wp[q];
            s = fmaf(xr[q * 4 + 0], wv.x, s);
            s = fmaf(xr[q * 4 + 1], wv.y, s);
            s = fmaf(xr[q * 4 + 2], wv.z, s);
            s = fmaf(xr[q * 4 + 3], wv.w, s);
        }
        float sp = fmaxf(s, 0.f) + log1pf(expf(-fabsf(s)));
        dtb[(size_t)row * NI + o] = sp + 1e-4f;
    }
}

// ---------------- window-softmax + gate + mean over last 8 steps
__global__ __launch_bounds__(256)
void fuse_kernel(const float* __restrict__ xc, const float* __restrict__ z,
                 const float* __restrict__ dt, const float* __restrict__ Dp,
                 float* __restrict__ comp)
{
    const int d = blockIdx.x * 256 + threadIdx.x;
    const int b = blockIdx.y;
    if (d >= DINNER) return;
    float xcv[15];
#pragma unroll
    for (int tt = 0; tt < 15; ++tt) xcv[tt] = xc[(size_t)(tt * 64 + b) * NI + d];
    const float Dpd = Dp[d];
    float acc = 0.f;
#pragma unroll
    for (int s = 0; s < 8; ++s) {
        float dval = dt[(size_t)(s * 64 + b) * NI + d];
        float zval = z[(size_t)(s * 64 + b) * NI + d];
        float e = expf(-dval);
        float w = 1.f, wsum = 0.f, lsum = 0.f;
#pragma unroll
        for (int k = 7; k >= 0; --k) {
            wsum += w;
            lsum = fmaf(w, xcv[s + k], lsum);
            w *= e;
        }
        float local = lsum / wsum;
        float ys = (local + Dpd * xcv[s + 7]) / (1.f + expf(-zval));
        acc += ys;
    }
    comp[(size_t)b * NI + d] = acc * 0.125f;
}

// ---------------- split-K out-projection (f32)
__global__ __launch_bounds__(256)
void gemm_nt_splitk(const float* __restrict__ A, int lda,
                    const float* __restrict__ B, int ldb,
                    float* __restrict__ Cp, int ldc,
                    int M, int N, int K, int kchunk)
{
    __shared__ float As[16][68];
    __shared__ float Bs[16][68];
    const int tid = threadIdx.x;
    const int tx = tid & 15, ty = tid >> 4;
    const int m0 = blockIdx.y * 64, n0 = blockIdx.x * 64;
    const int kbeg = blockIdx.z * kchunk;
    const int kend = min(K, kbeg + kchunk);
    float* C = Cp + (size_t)blockIdx.z * M * ldc;
    float acc[4][4] = {};
    for (int k0 = kbeg; k0 < kend; k0 += 16) {
#pragma unroll
        for (int u = 0; u < 4; ++u) {
            int idx = u * 256 + tid;
            int r = idx >> 4, kk = idx & 15;
            int gk = k0 + kk;
            float av = 0.f, bv = 0.f;
            if (gk < kend) {
                av = A[(size_t)(m0 + r) * lda + gk];
                int nn = n0 + r;
                bv = (nn < N) ? B[(size_t)nn * ldb + gk] : 0.f;
            }
            As[kk][r] = av;
            Bs[kk][r] = bv;
        }
        __syncthreads();
#pragma unroll
        for (int kk = 0; kk < 16; ++kk) {
            float4 a4 = *(const float4*)&As[kk][ty * 4];
            float4 b4 = *(const float4*)&Bs[kk][tx * 4];
            float a[4] = {a4.x, a4.y, a4.z, a4.w};
            float b[4] = {b4.x, b4.y, b4.z, b4.w};
#pragma unroll
            for (int i = 0; i < 4; ++i)
#pragma unroll
                for (int j = 0; j < 4; ++j)
                    acc[i][j] = fmaf(a[i], b[j], acc[i][j]);
        }
        __syncthreads();
    }
#pragma unroll
    for (int i = 0; i < 4; ++i) {
        int m = m0 + ty * 4 + i;
#pragma unroll
        for (int j = 0; j < 4; ++j) {
            int n = n0 + tx * 4 + j;
            if (n < N) C[(size_t)m * ldc + n] = acc[i][j];
        }
    }
}

// ---------------- splitk-reduce + bias + layernorm fused
__global__ __launch_bounds__(256)
void ln_kernel(const float* __restrict__ Cp,    // [16][64][2048] partials
               const float* __restrict__ b_out,
               const float* __restrict__ lw, const float* __restrict__ lb,
               float* __restrict__ out)
{
    const int b = blockIdx.x;
    const int tid = threadIdx.x;
    __shared__ float red[4];
    float v[8];
    float s = 0.f;
#pragma unroll
    for (int i = 0; i < 8; ++i) {
        int col = i * 256 + tid;
        float acc = b_out[col];
#pragma unroll
        for (int p = 0; p < OUT_SPLITS; ++p)
            acc += Cp[(size_t)p * 64 * 2048 + b * 2048 + col];
        v[i] = acc; s += acc;
    }
#pragma unroll
    for (int off = 32; off; off >>= 1) s += __shfl_down(s, off);
    if ((tid & 63) == 0) red[tid >> 6] = s;
    __syncthreads();
    float mu = (red[0] + red[1] + red[2] + red[3]) / 2048.f;
    float s2 = 0.f;
#pragma unroll
    for (int i = 0; i < 8; ++i) { float dd = v[i] - mu; s2 += dd * dd; }
#pragma unroll
    for (int off = 32; off; off >>= 1) s2 += __shfl_down(s2, off);
    __syncthreads();
    if ((tid & 63) == 0) red[tid >> 6] = s2;
    __syncthreads();
    float var = (red[0] + red[1] + red[2] + red[3]) / 2048.f;
    float inv = rsqrtf(var + 1e-5f);
#pragma unroll
    for (int i = 0; i < 8; ++i) {
        int dcol = i * 256 + tid;
        out[b * 2048 + dcol] = (v[i] - mu) * inv * lw[dcol] + lb[dcol];
    }
}

extern "C" void kernel_launch(void* const* d_in, const int* in_sizes, int n_in,
                              void* d_out, int out_size, void* d_ws, size_t ws_size,
                              hipStream_t stream)
{
    const float* x      = (const float*)d_in[0];
    const float* W_in   = (const float*)d_in[1];
    const float* b_in   = (const float*)d_in[2];
    const float* W_gate = (const float*)d_in[3];
    const float* b_gate = (const float*)d_in[4];
    const float* W_conv = (const float*)d_in[5];
    const float* b_conv = (const float*)d_in[6];
    const float* W_xp   = (const float*)d_in[7];
    const float* b_xp   = (const float*)d_in[8];
    const float* W_dt   = (const float*)d_in[9];
    const float* Dp     = (const float*)d_in[10];
    const float* W_out  = (const float*)d_in[11];
    const float* b_out  = (const float*)d_in[12];
    const float* ln_w   = (const float*)d_in[13];
    const float* ln_b   = (const float*)d_in[14];
    float* out = (float*)d_out;

    float* ws = (float*)d_ws;
    auto alloc = [&](size_t nf) { float* p = ws; ws += (nf + 255) & ~(size_t)255; return p; };
    unsigned short* A_x   = (unsigned short*)alloc((size_t)NROW_XI * DMODEL / 2);
    unsigned short* B_cat = (unsigned short*)alloc((size_t)NCAT * DMODEL / 2);
    unsigned short* B_cv  = (unsigned short*)alloc((size_t)4 * CONV_PLANE / 2);
    unsigned short* xi_bf = (unsigned short*)alloc((size_t)NROW_XI * NI / 2);
    float* zb   = alloc((size_t)NROW_Z * NI);
    float* comp = alloc((size_t)64 * NI);
    // aliases (stream-ordered lifetime):
    float* xcb     = (float*)B_cat;                    // 960*NI f32, after fused GEMM done
    float* outpart = (float*)B_cat + (size_t)960 * NI; // 16*64*2048 f32, disjoint from xcb
    float* dtb     = (float*)B_cv;                     // 512*NI f32, after conv done

    // 1) merged casts
    cast_all<<<CAST_B2, 256, 0, stream>>>(x + (size_t)(110 * 64) * DMODEL,
                                          W_in, W_gate, W_conv, A_x, B_cat, B_cv);
    // 2) fused xi|z MFMA GEMM: 360 xi tiles + 160 gate tiles
    gemm_mfma_fused<<<520, 256, 0, stream>>>(A_x, B_cat, b_in, b_gate, xi_bf, zb);
    // 3) conv MFMA + SiLU
    {
        dim3 grid(GNP / 128, 960 / 64, GROUPS); // 3 x 15 x 7
        conv_mfma<<<grid, 256, 0, stream>>>(xi_bf, B_cv, b_conv, xcb);
    }
    // 4) fused xproj+dt, then window-softmax fuse
    xproj_dt<<<512, 256, 0, stream>>>(xcb, W_xp, b_xp, W_dt, dtb);
    {
        dim3 grid((DINNER + 255) / 256, 64);
        fuse_kernel<<<grid, 256, 0, stream>>>(xcb, zb, dtb, Dp, comp);
    }
    // 5) out-projection (split-K 16) + fused reduce+LN
    {
        const int kchunk = (DINNER + OUT_SPLITS - 1) / OUT_SPLITS;  // 154
        dim3 grid(DMODEL / 64, 1, OUT_SPLITS);
        gemm_nt_splitk<<<grid, 256, 0, stream>>>(comp, NI, W_out, DINNER,
                                                 outpart, DMODEL, 64, DMODEL, DINNER, kchunk);
    }
    ln_kernel<<<64, 256, 0, stream>>>(outpart, b_out, ln_w, ln_b, out);
}

// Round 6
// 135.932 us; speedup vs baseline: 8.6141x; 1.1571x over previous
//
#include <hip/hip_runtime.h>
#include <math.h>
#include <stdint.h>

// ---- problem constants ----
#define DMODEL 2048
#define DINNER 2457
#define NI     2464      // padded row stride for [*, DINNER] buffers (=7*352)
#define GROUPS 7
#define GCH    351       // channels per group
#define GP     352       // K-padded channels per group (bf16 layouts)
#define GNP    384       // N-padded channels per group (conv B rows)
#define NROW_XI 1152     // 18*64 rows (t=110..127)
#define NROW_Z  512      // 8*64 rows (t=120..127)
#define NCAT   5120      // fused GEMM N: W_in -> [0,2560), W_gate -> [2560,5120)
#define GATE0  2560
#define OUT_SPLITS 16
#define CONV_PLANE (GROUPS * GNP * GP)   // per-tap conv-B plane elems (2688*352)

typedef __attribute__((ext_vector_type(8))) __bf16 bf16x8;
typedef __attribute__((ext_vector_type(4))) float f32x4;
typedef __attribute__((ext_vector_type(8))) unsigned short ushort8;

__device__ inline unsigned short f2bf(float f) {
    union { float f; unsigned int u; } v; v.f = f;
    unsigned int u = v.u;
    return (unsigned short)((u + 0x7FFFu + ((u >> 16) & 1u)) >> 16);  // RNE
}

// LDS swizzle: rows of 32 shorts (64B = 4x16B slots); LDS position p of row r
// holds global slot p ^ ((r>>1)&3). Source pre-swizzled, read swizzled (rule #21).
__device__ inline int lds_addr(int row, int slot) {
    return row * 32 + ((slot ^ ((row >> 1) & 3)) << 3);
}

// async global->LDS, 16B per lane; lds dest is wave-uniform base + lane*16
__device__ __forceinline__ void gload16(const unsigned short* g, unsigned short* l) {
    __builtin_amdgcn_global_load_lds(
        (const __attribute__((address_space(1))) unsigned int*)g,
        (__attribute__((address_space(3))) unsigned int*)l, 16, 0, 0);
}

// ---------------- merged casts ----------------
#define CAST_B0 1152
#define CAST_B1 6066
#define CAST_B2 9435
__global__ __launch_bounds__(256)
void cast_all(const float* __restrict__ x110,
              const float* __restrict__ Win, const float* __restrict__ Wg,
              const float* __restrict__ Wc,
              unsigned short* __restrict__ A_x,
              unsigned short* __restrict__ B_cat,
              unsigned short* __restrict__ B_cv)
{
    int bx = blockIdx.x;
    if (bx < CAST_B0) {
        size_t t = (size_t)bx * 256 + threadIdx.x;
        const float4* s = (const float4*)x110 + t * 2;
        float4 a = s[0], b = s[1];
        ushort8 o;
        o[0]=f2bf(a.x); o[1]=f2bf(a.y); o[2]=f2bf(a.z); o[3]=f2bf(a.w);
        o[4]=f2bf(b.x); o[5]=f2bf(b.y); o[6]=f2bf(b.z); o[7]=f2bf(b.w);
        *(ushort8*)(A_x + t * 8) = o;
    } else if (bx < CAST_B1) {
        int idx = bx - CAST_B0;
        int half = idx >= DINNER;
        int cb = half ? idx - DINNER : idx;
        const float* src = half ? Wg : Win;
        size_t t = (size_t)cb * 256 + threadIdx.x;
        size_t elem = t * 8;
        size_t doff = elem + (half ? (size_t)GATE0 * DMODEL : 0);
        const float4* s = (const float4*)(src + elem);
        float4 a = s[0], b = s[1];
        ushort8 o;
        o[0]=f2bf(a.x); o[1]=f2bf(a.y); o[2]=f2bf(a.z); o[3]=f2bf(a.w);
        o[4]=f2bf(b.x); o[5]=f2bf(b.y); o[6]=f2bf(b.z); o[7]=f2bf(b.w);
        *(ushort8*)(B_cat + doff) = o;
    } else {
        int t = (bx - CAST_B1) * 256 + threadIdx.x;
        if (t >= DINNER * GCH) return;
        int oc = t / GCH, i = t - oc * GCH;
        float4 w = *(const float4*)(Wc + (size_t)t * 4);
        int g = oc / GCH, ol = oc - g * GCH;
        size_t base = (size_t)(g * GNP + ol) * GP + i;
        B_cv[0 * (size_t)CONV_PLANE + base] = f2bf(w.x);
        B_cv[1 * (size_t)CONV_PLANE + base] = f2bf(w.y);
        B_cv[2 * (size_t)CONV_PLANE + base] = f2bf(w.z);
        B_cv[3 * (size_t)CONV_PLANE + base] = f2bf(w.w);
        if (i == GCH - 1) {
            B_cv[0 * (size_t)CONV_PLANE + base + 1] = 0;
            B_cv[1 * (size_t)CONV_PLANE + base + 1] = 0;
            B_cv[2 * (size_t)CONV_PLANE + base + 1] = 0;
            B_cv[3 * (size_t)CONV_PLANE + base + 1] = 0;
        }
    }
}

// ---------------- fused xi|z bf16 MFMA GEMM ----------------
// tile 128x128, 4 waves (wave-tile 64x64, 16 MFMA : 8 ds_read_b128).
// 3-buffer depth-2 counted-vmcnt pipeline; one raw barrier per K-step, no drain.
// Grid 260: 180 xi tiles (n-major) + 80 gate tiles (rows>=640 only).
#define NKF 64   // 2048/32
__global__ __launch_bounds__(256)
void gemm_mfma_fused(const unsigned short* __restrict__ A,   // [1152][2048] bf16
                     const unsigned short* __restrict__ B,   // [5120][2048] bf16
                     const float* __restrict__ b_in,
                     const float* __restrict__ b_gate,
                     unsigned short* __restrict__ xi,        // [1152][NI] bf16 group-padded
                     float* __restrict__ zb)                 // [512][NI] f32
{
    __shared__ unsigned short sm[3 * 256 * 32];   // 3 bufs x (A128 + B128 rows) x 64B = 48KB
    const int tid = threadIdx.x;
    const int w = tid >> 6, l = tid & 63;
    const int l15 = l & 15, l4 = l >> 4;
    const int wm = w >> 1, wn = w & 1;

    // bijective XCD-chunked swizzle (260 = 8*32+4): XCD k gets a contiguous
    // logical range; logical order is n-major so same-B-panel blocks colocate.
    const int orig = blockIdx.x;
    const int xcd = orig & 7, lo = orig >> 3;
    const int logical = (xcd < 4 ? xcd * 33 : 132 + (xcd - 4) * 32) + lo;
    int mt, nt, is_gate;
    if (logical < 180) { nt = logical / 9; mt = logical % 9; is_gate = 0; }
    else { int b2 = logical - 180; nt = 20 + b2 / 4; mt = 5 + b2 % 4; is_gate = 1; }
    const int m0 = mt * 128, n0 = nt * 128;

    // staging: seg = 16 rows (1KB); wave w stages A segs {w,w+4}, B segs {w,w+4}
    const int lr = l >> 2, slot = l & 3;
    const int r0 = w * 16 + lr, r1 = r0 + 64;
    const int xo0 = (slot ^ ((r0 >> 1) & 3)) << 3;
    const int xo1 = (slot ^ ((r1 >> 1) & 3)) << 3;
    const unsigned short* gA0 = A + (size_t)(m0 + r0) * DMODEL + xo0;
    const unsigned short* gA1 = A + (size_t)(m0 + r1) * DMODEL + xo1;
    const unsigned short* gB0 = B + (size_t)(n0 + r0) * DMODEL + xo0;
    const unsigned short* gB1 = B + (size_t)(n0 + r1) * DMODEL + xo1;
    unsigned short* dA0 = sm + w * 512;
    unsigned short* dA1 = sm + (w + 4) * 512;
    unsigned short* dB0 = sm + 4096 + w * 512;
    unsigned short* dB1 = sm + 4096 + (w + 4) * 512;

#define STAGE_G(buf, ks) do { int _o = (ks) * 32, _b = (buf) * 8192; \
    gload16(gA0 + _o, dA0 + _b); gload16(gA1 + _o, dA1 + _b); \
    gload16(gB0 + _o, dB0 + _b); gload16(gB1 + _o, dB1 + _b); } while (0)

    f32x4 acc[4][4] = {};
    auto compute = [&](const unsigned short* base) {
        bf16x8 af[4], bfr[4];
#pragma unroll
        for (int f = 0; f < 4; ++f)
            af[f] = *(const bf16x8*)(base + lds_addr(wm * 64 + f * 16 + l15, l4));
#pragma unroll
        for (int j = 0; j < 4; ++j)
            bfr[j] = *(const bf16x8*)(base + 4096 + lds_addr(wn * 64 + j * 16 + l15, l4));
#pragma unroll
        for (int i = 0; i < 4; ++i)
#pragma unroll
            for (int j = 0; j < 4; ++j)
                acc[i][j] = __builtin_amdgcn_mfma_f32_16x16x32_bf16(af[i], bfr[j], acc[i][j], 0, 0, 0);
    };

    STAGE_G(0, 0);
    STAGE_G(1, 1);
    int rbuf = 0, sbuf = 2;
    for (int ks = 0; ks < NKF - 1; ++ks) {
        asm volatile("s_waitcnt vmcnt(4)" ::: "memory");   // own tile-ks loads done
        __builtin_amdgcn_s_barrier();                       // everyone's done; no drain
        if (ks < NKF - 2) STAGE_G(sbuf, ks + 2);            // keep 2 tiles in flight
        compute(sm + rbuf * 8192);
        rbuf = rbuf == 2 ? 0 : rbuf + 1;
        sbuf = sbuf == 2 ? 0 : sbuf + 1;
    }
    asm volatile("s_waitcnt vmcnt(0)" ::: "memory");        // last tile
    __builtin_amdgcn_s_barrier();
    compute(sm + rbuf * 8192);
#undef STAGE_G

    if (!is_gate) {
#pragma unroll
        for (int j = 0; j < 4; ++j) {
            int colg = n0 + wn * 64 + j * 16 + l15;
            if (colg < DINNER) {
                int g = colg / GCH, ci = colg - g * GCH;
                float bias = b_in[colg];
                size_t dco = (size_t)(g * GP + ci);
#pragma unroll
                for (int i = 0; i < 4; ++i)
#pragma unroll
                    for (int r = 0; r < 4; ++r) {
                        int row = m0 + wm * 64 + i * 16 + l4 * 4 + r;
                        xi[(size_t)row * NI + dco] = f2bf(acc[i][j][r] + bias);
                        if (ci == GCH - 1) xi[(size_t)row * NI + dco + 1] = 0;  // K-pad
                    }
            }
        }
    } else {
#pragma unroll
        for (int j = 0; j < 4; ++j) {
            int ng = n0 + wn * 64 + j * 16 + l15 - GATE0;
            if (ng < DINNER) {
                float bias = b_gate[ng];
#pragma unroll
                for (int i = 0; i < 4; ++i)
#pragma unroll
                    for (int r = 0; r < 4; ++r) {
                        int row = m0 + wm * 64 + i * 16 + l4 * 4 + r;  // >= 640 always
                        zb[(size_t)(row - 640) * NI + ng] = acc[i][j][r] + bias;
                    }
            }
        }
    }
}

// ---------------- grouped causal conv: 4 shifted-tap MFMA GEMMs + SiLU ------
// tile 64x128, 4 waves (wave-tile 32x64); 3-buffer depth-2 counted-vmcnt.
#define NKC 44
__global__ __launch_bounds__(256)
void conv_mfma(const unsigned short* __restrict__ xi,  // [1152][NI] bf16
               const unsigned short* __restrict__ Bc,  // [4][2688][352] bf16
               const float* __restrict__ bc,
               float* __restrict__ xcb)                // [960][NI] f32 (post-SiLU)
{
    __shared__ unsigned short sm[3 * 192 * 32];   // 3 bufs x (A64 + B128 rows) x 64B = 36KB
    const int tid = threadIdx.x;
    const int w = tid >> 6, l = tid & 63;
    const int l15 = l & 15, l4 = l >> 4;
    const int wm = w >> 1, wn = w & 1;

    // bijective XCD-chunked swizzle (315 = 8*39+3); logical m-major within (g,nt)
    const int orig = blockIdx.x;
    const int xcd = orig & 7, lo = orig >> 3;
    const int logical = (xcd < 3 ? xcd * 40 : 120 + (xcd - 3) * 39) + lo;
    const int gn = logical / 15, mt = logical % 15;
    const int g = gn / 3, nt = gn % 3;
    const int m0 = mt * 64;
    const int n0l = nt * 128;

    const int lr = l >> 2, slot = l & 3;
    const int rA = w * 16 + lr;            // A rows 0..63 (seg w)
    const int rB0 = rA, rB1 = rA + 64;     // B segs w, w+4
    const int xoA  = (slot ^ ((rA  >> 1) & 3)) << 3;
    const int xoB1 = (slot ^ ((rB1 >> 1) & 3)) << 3;
    const unsigned short* gAb = xi + (size_t)(m0 + rA) * NI + g * GP + xoA;
    const unsigned short* gB0 = Bc + (size_t)(g * GNP + n0l + rB0) * GP + xoA;
    const unsigned short* gB1 = Bc + (size_t)(g * GNP + n0l + rB1) * GP + xoB1;
    unsigned short* dA  = sm + w * 512;
    unsigned short* dB0 = sm + 2048 + w * 512;
    unsigned short* dB1 = sm + 2048 + (w + 4) * 512;

#define STAGE_C(buf, ks) do { \
    int _tap = (ks) / 11, _kc = (ks) - _tap * 11, _b = (buf) * 6144; \
    size_t _ao = (size_t)(64 * _tap) * NI + _kc * 32; \
    size_t _bo = (size_t)_tap * CONV_PLANE + _kc * 32; \
    gload16(gAb + _ao, dA  + _b); \
    gload16(gB0 + _bo, dB0 + _b); \
    gload16(gB1 + _bo, dB1 + _b); } while (0)

    f32x4 acc[2][4] = {};
    auto compute = [&](const unsigned short* base) {
        bf16x8 af[2], bfr[4];
#pragma unroll
        for (int f = 0; f < 2; ++f)
            af[f] = *(const bf16x8*)(base + lds_addr(wm * 32 + f * 16 + l15, l4));
#pragma unroll
        for (int j = 0; j < 4; ++j)
            bfr[j] = *(const bf16x8*)(base + 2048 + lds_addr(wn * 64 + j * 16 + l15, l4));
#pragma unroll
        for (int i = 0; i < 2; ++i)
#pragma unroll
            for (int j = 0; j < 4; ++j)
                acc[i][j] = __builtin_amdgcn_mfma_f32_16x16x32_bf16(af[i], bfr[j], acc[i][j], 0, 0, 0);
    };

    STAGE_C(0, 0);
    STAGE_C(1, 1);
    int rbuf = 0, sbuf = 2;
    for (int ks = 0; ks < NKC - 1; ++ks) {
        asm volatile("s_waitcnt vmcnt(3)" ::: "memory");
        __builtin_amdgcn_s_barrier();
        if (ks < NKC - 2) STAGE_C(sbuf, ks + 2);
        compute(sm + rbuf * 6144);
        rbuf = rbuf == 2 ? 0 : rbuf + 1;
        sbuf = sbuf == 2 ? 0 : sbuf + 1;
    }
    asm volatile("s_waitcnt vmcnt(0)" ::: "memory");
    __builtin_amdgcn_s_barrier();
    compute(sm + rbuf * 6144);
#undef STAGE_C

#pragma unroll
    for (int j = 0; j < 4; ++j) {
        int ocl = n0l + wn * 64 + j * 16 + l15;
        if (ocl < GCH) {
            int ch = g * GCH + ocl;
            float bias = bc[ch];
#pragma unroll
            for (int i = 0; i < 2; ++i)
#pragma unroll
                for (int r = 0; r < 4; ++r) {
                    int row = m0 + wm * 32 + i * 16 + l4 * 4 + r;
                    float v = acc[i][j][r] + bias;
                    xcb[(size_t)row * NI + ch] = v / (1.f + expf(-v));
                }
        }
    }
}

// ---------------- fused xproj + dt ----------------
__global__ __launch_bounds__(256)
void xproj_dt(const float* __restrict__ xc,    // [960][NI], rows 448.. = t 24..31
              const float* __restrict__ Wxp,   // [48][DINNER]
              const float* __restrict__ bxp,
              const float* __restrict__ Wdt,   // [DINNER][32]
              float* __restrict__ dtb)         // [512][NI]
{
    const int row = blockIdx.x;
    const float* a = xc + (size_t)(448 + row) * NI;
    float acc[32];
#pragma unroll
    for (int o = 0; o < 32; ++o) acc[o] = 0.f;
    for (int k = threadIdx.x; k < DINNER; k += 256) {
        float av = a[k];
#pragma unroll
        for (int o = 0; o < 32; ++o)
            acc[o] = fmaf(av, Wxp[(size_t)o * DINNER + k], acc[o]);
    }
#pragma unroll
    for (int o = 0; o < 32; ++o)
#pragma unroll
        for (int off = 32; off; off >>= 1)
            acc[o] += __shfl_down(acc[o], off);
    __shared__ float red[4][32];
    __shared__ float xp[32];
    const int wid = threadIdx.x >> 6, lane = threadIdx.x & 63;
    if (lane == 0)
#pragma unroll
        for (int o = 0; o < 32; ++o) red[wid][o] = acc[o];
    __syncthreads();
    if (threadIdx.x < 32) {
        int o = threadIdx.x;
        xp[o] = red[0][o] + red[1][o] + red[2][o] + red[3][o] + bxp[o];
    }
    __syncthreads();
    float xr[32];
#pragma unroll
    for (int k = 0; k < 32; ++k) xr[k] = xp[k];
    for (int o = threadIdx.x; o < DINNER; o += 256) {
        const float4* wp = (const float4*)(Wdt + (size_t)o * 32);
        float s = 0.f;
#pragma unroll
        for (int q = 0; q < 8; ++q) {
            float4 wv = wp[q];
            s = fmaf(xr[q * 4 + 0], wv.x, s);
            s = fmaf(xr[q * 4 + 1], wv.y, s);
            s = fmaf(xr[q * 4 + 2], wv.z, s);
            s = fmaf(xr[q * 4 + 3], wv.w, s);
        }
        float sp = fmaxf(s, 0.f) + log1pf(expf(-fabsf(s)));
        dtb[(size_t)row * NI + o] = sp + 1e-4f;
    }
}

// ---------------- window-softmax + gate + mean over last 8 steps
__global__ __launch_bounds__(256)
void fuse_kernel(const float* __restrict__ xc, const float* __restrict__ z,
                 const float* __restrict__ dt, const float* __restrict__ Dp,
                 float* __restrict__ comp)
{
    const int d = blockIdx.x * 256 + threadIdx.x;
    const int b = blockIdx.y;
    if (d >= DINNER) return;
    float xcv[15];
#pragma unroll
    for (int tt = 0; tt < 15; ++tt) xcv[tt] = xc[(size_t)(tt * 64 + b) * NI + d];
    const float Dpd = Dp[d];
    float acc = 0.f;
#pragma unroll
    for (int s = 0; s < 8; ++s) {
        float dval = dt[(size_t)(s * 64 + b) * NI + d];
        float zval = z[(size_t)(s * 64 + b) * NI + d];
        float e = expf(-dval);
        float w = 1.f, wsum = 0.f, lsum = 0.f;
#pragma unroll
        for (int k = 7; k >= 0; --k) {
            wsum += w;
            lsum = fmaf(w, xcv[s + k], lsum);
            w *= e;
        }
        float local = lsum / wsum;
        float ys = (local + Dpd * xcv[s + 7]) / (1.f + expf(-zval));
        acc += ys;
    }
    comp[(size_t)b * NI + d] = acc * 0.125f;
}

// ---------------- split-K out-projection (f32)
__global__ __launch_bounds__(256)
void gemm_nt_splitk(const float* __restrict__ A, int lda,
                    const float* __restrict__ B, int ldb,
                    float* __restrict__ Cp, int ldc,
                    int M, int N, int K, int kchunk)
{
    __shared__ float As[16][68];
    __shared__ float Bs[16][68];
    const int tid = threadIdx.x;
    const int tx = tid & 15, ty = tid >> 4;
    const int m0 = blockIdx.y * 64, n0 = blockIdx.x * 64;
    const int kbeg = blockIdx.z * kchunk;
    const int kend = min(K, kbeg + kchunk);
    float* C = Cp + (size_t)blockIdx.z * M * ldc;
    float acc[4][4] = {};
    for (int k0 = kbeg; k0 < kend; k0 += 16) {
#pragma unroll
        for (int u = 0; u < 4; ++u) {
            int idx = u * 256 + tid;
            int r = idx >> 4, kk = idx & 15;
            int gk = k0 + kk;
            float av = 0.f, bv = 0.f;
            if (gk < kend) {
                av = A[(size_t)(m0 + r) * lda + gk];
                int nn = n0 + r;
                bv = (nn < N) ? B[(size_t)nn * ldb + gk] : 0.f;
            }
            As[kk][r] = av;
            Bs[kk][r] = bv;
        }
        __syncthreads();
#pragma unroll
        for (int kk = 0; kk < 16; ++kk) {
            float4 a4 = *(const float4*)&As[kk][ty * 4];
            float4 b4 = *(const float4*)&Bs[kk][tx * 4];
            float a[4] = {a4.x, a4.y, a4.z, a4.w};
            float b[4] = {b4.x, b4.y, b4.z, b4.w};
#pragma unroll
            for (int i = 0; i < 4; ++i)
#pragma unroll
                for (int j = 0; j < 4; ++j)
                    acc[i][j] = fmaf(a[i], b[j], acc[i][j]);
        }
        __syncthreads();
    }
#pragma unroll
    for (int i = 0; i < 4; ++i) {
        int m = m0 + ty * 4 + i;
#pragma unroll
        for (int j = 0; j < 4; ++j) {
            int n = n0 + tx * 4 + j;
            if (n < N) C[(size_t)m * ldc + n] = acc[i][j];
        }
    }
}

// ---------------- splitk-reduce + bias + layernorm fused
__global__ __launch_bounds__(256)
void ln_kernel(const float* __restrict__ Cp,    // [16][64][2048] partials
               const float* __restrict__ b_out,
               const float* __restrict__ lw, const float* __restrict__ lb,
               float* __restrict__ out)
{
    const int b = blockIdx.x;
    const int tid = threadIdx.x;
    __shared__ float red[4];
    float v[8];
    float s = 0.f;
#pragma unroll
    for (int i = 0; i < 8; ++i) {
        int col = i * 256 + tid;
        float acc = b_out[col];
#pragma unroll
        for (int p = 0; p < OUT_SPLITS; ++p)
            acc += Cp[(size_t)p * 64 * 2048 + b * 2048 + col];
        v[i] = acc; s += acc;
    }
#pragma unroll
    for (int off = 32; off; off >>= 1) s += __shfl_down(s, off);
    if ((tid & 63) == 0) red[tid >> 6] = s;
    __syncthreads();
    float mu = (red[0] + red[1] + red[2] + red[3]) / 2048.f;
    float s2 = 0.f;
#pragma unroll
    for (int i = 0; i < 8; ++i) { float dd = v[i] - mu; s2 += dd * dd; }
#pragma unroll
    for (int off = 32; off; off >>= 1) s2 += __shfl_down(s2, off);
    __syncthreads();
    if ((tid & 63) == 0) red[tid >> 6] = s2;
    __syncthreads();
    float var = (red[0] + red[1] + red[2] + red[3]) / 2048.f;
    float inv = rsqrtf(var + 1e-5f);
#pragma unroll
    for (int i = 0; i < 8; ++i) {
        int dcol = i * 256 + tid;
        out[b * 2048 + dcol] = (v[i] - mu) * inv * lw[dcol] + lb[dcol];
    }
}

extern "C" void kernel_launch(void* const* d_in, const int* in_sizes, int n_in,
                              void* d_out, int out_size, void* d_ws, size_t ws_size,
                              hipStream_t stream)
{
    const float* x      = (const float*)d_in[0];
    const float* W_in   = (const float*)d_in[1];
    const float* b_in   = (const float*)d_in[2];
    const float* W_gate = (const float*)d_in[3];
    const float* b_gate = (const float*)d_in[4];
    const float* W_conv = (const float*)d_in[5];
    const float* b_conv = (const float*)d_in[6];
    const float* W_xp   = (const float*)d_in[7];
    const float* b_xp   = (const float*)d_in[8];
    const float* W_dt   = (const float*)d_in[9];
    const float* Dp     = (const float*)d_in[10];
    const float* W_out  = (const float*)d_in[11];
    const float* b_out  = (const float*)d_in[12];
    const float* ln_w   = (const float*)d_in[13];
    const float* ln_b   = (const float*)d_in[14];
    float* out = (float*)d_out;

    float* ws = (float*)d_ws;
    auto alloc = [&](size_t nf) { float* p = ws; ws += (nf + 255) & ~(size_t)255; return p; };
    unsigned short* A_x   = (unsigned short*)alloc((size_t)NROW_XI * DMODEL / 2);
    unsigned short* B_cat = (unsigned short*)alloc((size_t)NCAT * DMODEL / 2);
    unsigned short* B_cv  = (unsigned short*)alloc((size_t)4 * CONV_PLANE / 2);
    unsigned short* xi_bf = (unsigned short*)alloc((size_t)NROW_XI * NI / 2);
    float* zb   = alloc((size_t)NROW_Z * NI);
    float* comp = alloc((size_t)64 * NI);
    // aliases (stream-ordered lifetime):
    float* xcb     = (float*)B_cat;                    // 960*NI f32, after fused GEMM done
    float* outpart = (float*)B_cat + (size_t)960 * NI; // 16*64*2048 f32, disjoint from xcb
    float* dtb     = (float*)B_cv;                     // 512*NI f32, after conv done

    // 1) merged casts
    cast_all<<<CAST_B2, 256, 0, stream>>>(x + (size_t)(110 * 64) * DMODEL,
                                          W_in, W_gate, W_conv, A_x, B_cat, B_cv);
    // 2) fused xi|z MFMA GEMM: 180 xi tiles + 80 gate tiles, 128x128
    gemm_mfma_fused<<<260, 256, 0, stream>>>(A_x, B_cat, b_in, b_gate, xi_bf, zb);
    // 3) conv MFMA + SiLU (flat grid, XCD-swizzled)
    conv_mfma<<<315, 256, 0, stream>>>(xi_bf, B_cv, b_conv, xcb);
    // 4) fused xproj+dt, then window-softmax fuse
    xproj_dt<<<512, 256, 0, stream>>>(xcb, W_xp, b_xp, W_dt, dtb);
    {
        dim3 grid((DINNER + 255) / 256, 64);
        fuse_kernel<<<grid, 256, 0, stream>>>(xcb, zb, dtb, Dp, comp);
    }
    // 5) out-projection (split-K 16) + fused reduce+LN
    {
        const int kchunk = (DINNER + OUT_SPLITS - 1) / OUT_SPLITS;  // 154
        dim3 grid(DMODEL / 64, 1, OUT_SPLITS);
        gemm_nt_splitk<<<grid, 256, 0, stream>>>(comp, NI, W_out, DINNER,
                                                 outpart, DMODEL, 64, DMODEL, DINNER, kchunk);
    }
    ln_kernel<<<64, 256, 0, stream>>>(outpart, b_out, ln_w, ln_b, out);
}